// Round 10
// baseline (581.809 us; speedup 1.0000x reference)
//
#include <hip/hip_runtime.h>

typedef unsigned short u16;
typedef unsigned int u32;
typedef unsigned long long u64;

typedef float f32x4 __attribute__((ext_vector_type(4)));
typedef short bf16x8 __attribute__((ext_vector_type(8)));

#define BB 8
#define NQ 1024
#define NK 256
#define HH 8
#define KD 544   // padded score-dot length (11*48=528 -> 544 = 17*32)

__device__ __forceinline__ float bf2f(u16 u) {
  union { u32 i; float f; } v; v.i = ((u32)u) << 16; return v.f;
}
__device__ __forceinline__ u16 f2bf(float f) {
  union { u32 i; float f; } v; v.f = f;
  u32 i = v.i;
  return (u16)((i + 0x7FFFu + ((i >> 16) & 1u)) >> 16);
}
__device__ __forceinline__ float softplusf(float d) {
  return (d > 20.f) ? d : log1pf(__expf(d));
}

// grade per component c (GRADE_IDX), nibble-packed
#define GRADE_TAB 0x4333322222211110ULL
// active component for score-slot s (slots 0..10 = INNER(8) then POINT(3))
#define ACT_TAB   0xDCBEA984320ULL
__device__ __forceinline__ int grade_of(int c) { return (int)((GRADE_TAB >> (c * 4)) & 15ULL); }
__device__ __forceinline__ int act_of(int s) { return (int)((ACT_TAB >> (s * 4)) & 15ULL); }

constexpr float INV_S384 = 0.05103103630798288f; // 1/sqrt(8*48)

// ---------------------------------------------------------------------------
// rms_kernel: rscale[row] = rsqrt(mean_i sum_c x^2 /48 + eps). 32 rows/block.
// ---------------------------------------------------------------------------
__global__ __launch_bounds__(256) void rms_kernel(const float* __restrict__ hidden,
                                                  float* __restrict__ rscale) {
  const int t = threadIdx.x;
  const int row = blockIdx.x * 32 + (t >> 3);
  const int l = t & 7;
  const float4* src = (const float4*)(hidden + (size_t)row * 768);
  float s = 0.f;
#pragma unroll
  for (int k = 0; k < 24; k++) {
    float4 v = src[l + 8 * k];
    s += v.x * v.x + v.y * v.y + v.z * v.z + v.w * v.w;
  }
#pragma unroll
  for (int off = 4; off; off >>= 1) s += __shfl_xor(s, off, 8);
  if (l == 0) rscale[row] = rsqrtf(s * (1.f / 48.f) + 1e-6f);
}

// ---------------------------------------------------------------------------
// wB_kernel: WqB[g][o][64] / WkvB[g][o][64] bf16 (K padded 48->64, zeros) for
// MFMA B-frags; WoB = bf16(Wo) (K=384 layout, unchanged).
// ---------------------------------------------------------------------------
__global__ __launch_bounds__(256) void wB_kernel(
    const float* __restrict__ Wq, const float* __restrict__ Wkv,
    const float* __restrict__ Wo, u16* __restrict__ WqB,
    u16* __restrict__ WkvB, u16* __restrict__ WoB) {
  int idx = blockIdx.x * 256 + threadIdx.x;
  const int NA = 5 * 384 * 64, NB = 5 * 768 * 64, NC = 5 * 48 * 384;
  if (idx < NA) {
    int g = idx / (384 * 64);
    int rem = idx - g * 384 * 64;
    int o = rem >> 6, j = rem & 63;
    WqB[idx] = (j < 48) ? f2bf(Wq[((size_t)g * 384 + o) * 48 + j]) : (u16)0;
  } else if (idx < NA + NB) {
    int k = idx - NA;
    int g = k / (768 * 64);
    int rem = k - g * 768 * 64;
    int o = rem >> 6, j = rem & 63;
    WkvB[k] = (j < 48) ? f2bf(Wkv[((size_t)g * 768 + o) * 48 + j]) : (u16)0;
  } else if (idx < NA + NB + NC) {
    int k = idx - NA - NB;
    WoB[k] = f2bf(Wo[k]);
  }
}

// ---------------------------------------------------------------------------
// xJ_kernel: x[row][i*16+c] (f32) -> xJ[c][row][64] bf16 (48 real i + 16 zero
// pad), optional RMS*lnw fold.  block = 64 rows via 4 chunks of 16.
// ---------------------------------------------------------------------------
__global__ __launch_bounds__(256) void xJ_kernel(
    const float* __restrict__ src, u16* __restrict__ dst,
    const float* __restrict__ rscale, const float* __restrict__ lnw,
    int NR, int norm) {
  __shared__ __align__(16) float ls[16 * 772];
  __shared__ float rs_s[16];
  const int t = threadIdx.x;
  const int row0 = blockIdx.x * 64;
  const int row16 = t & 15, c = t >> 4;
  for (int chunk = 0; chunk < 4; chunk++) {
    const int r0c = row0 + chunk * 16;
    __syncthreads();
    if (t < 16) rs_s[t] = norm ? rscale[r0c + t] : 1.f;
#pragma unroll
    for (int k = 0; k < 12; k++) {
      int f = t + 256 * k;
      int r = f / 192, j = f - r * 192;
      *(float4*)&ls[r * 772 + j * 4] =
          *(const float4*)(src + (size_t)(r0c + r) * 768 + j * 4);
    }
    __syncthreads();
    const float rsv = rs_s[row16];
    u16 buf[64];
#pragma unroll
    for (int i = 0; i < 48; i++) {
      float v = ls[row16 * 772 + i * 16 + c];
      if (norm) v *= rsv * lnw[i];
      buf[i] = f2bf(v);
    }
#pragma unroll
    for (int i = 48; i < 64; i++) buf[i] = 0;
    u16* dp = dst + ((size_t)c * NR + r0c + row16) * 64;
#pragma unroll
    for (int j4 = 0; j4 < 8; j4++) *(uint4*)(dp + j4 * 8) = *(uint4*)&buf[j4 * 8];
  }
}

// ---------------------------------------------------------------------------
// q_mfma: grid (128 rowblks of 64, 11 slots).  D[64 rows][384 o] = xq[c] (A)
// x WqB[g] (B), K=64.  Epilogue: scale(+bias) -> LDS -> 96B row-chunk stores
// into qsel (slot-10 blocks also zero the [528,544) pad).
// ---------------------------------------------------------------------------
#define QSTR 392
__global__ __launch_bounds__(256) void q_mfma(
    const u16* __restrict__ xq, const u16* __restrict__ WqB,
    const float* __restrict__ bq, const float* __restrict__ daa,
    u16* __restrict__ qsel) {
  __shared__ __align__(16) u16 es[4 * 16 * QSTR];  // 50.2 KB
  const int t = threadIdx.x;
  const int w = t >> 6, lane = t & 63, m16 = lane & 15, quad = lane >> 4;
  const int slot = blockIdx.y;
  const int c = act_of(slot), g = grade_of(c);
  const int row0 = blockIdx.x * 64;
  const int b = row0 >> 10, n0 = row0 & 1023;
  f32x4 acc[24];
#pragma unroll
  for (int nt = 0; nt < 24; nt++) acc[nt] = (f32x4)0.f;
  const u16* ap = xq + ((size_t)c * 8192 + row0 + w * 16 + m16) * 64 + quad * 8;
  const u16* wb = WqB + (size_t)g * 384 * 64 + (size_t)m16 * 64 + quad * 8;
#pragma unroll
  for (int ks = 0; ks < 2; ks++) {
    bf16x8 af = *(const bf16x8*)(ap + ks * 32);
#pragma unroll
    for (int nt = 0; nt < 24; nt++) {
      bf16x8 bf = *(const bf16x8*)(wb + (size_t)nt * 16 * 64 + ks * 32);
      acc[nt] = __builtin_amdgcn_mfma_f32_16x16x32_bf16(af, bf, acc[nt], 0, 0, 0);
    }
  }
#pragma unroll
  for (int nt = 0; nt < 24; nt++) {
    const int o = nt * 16 + m16;
    const int h = o / 48;
    const float sc = (slot < 8) ? INV_S384 : (2.f * softplusf(daa[h]) * (1.f / 48.f));
    const float bias = (slot == 0) ? bq[o] : 0.f;
#pragma unroll
    for (int rr = 0; rr < 4; rr++)
      es[(w * 16 + quad * 4 + rr) * QSTR + o] = f2bf((acc[nt][rr] + bias) * sc);
  }
  __syncthreads();
  for (int ch = t; ch < 512; ch += 256) {
    int r = ch >> 3, h = ch & 7;
    const uint4* sr = (const uint4*)&es[r * QSTR + h * 48];
    u16* dst = qsel + ((size_t)(b * 8 + h) * NQ + n0 + r) * KD + slot * 48;
#pragma unroll
    for (int j = 0; j < 6; j++) ((uint4*)dst)[j] = sr[j];
    if (slot == 10) {
      uint4 z = {0u, 0u, 0u, 0u};
      ((uint4*)dst)[6] = z;  // [528,536)
      ((uint4*)dst)[7] = z;  // [536,544)
    }
  }
}

// ---------------------------------------------------------------------------
// kv_mfma: grid (32 keyblks of 64, 27 tasks).  task<11: k-slot -> ksel (same
// structure as q_mfma, no scale).  task>=11: v component c=task-11 -> vT via
// [o][key] LDS staging (stride 72) and 8B key-contiguous stores.
// ---------------------------------------------------------------------------
#define VSTR 72
__global__ __launch_bounds__(256) void kv_mfma(
    const u16* __restrict__ xv, const u16* __restrict__ WkvB,
    const float* __restrict__ bkv, u16* __restrict__ ksel,
    u16* __restrict__ vT) {
  __shared__ __align__(16) u16 es[384 * VSTR];  // 55.3 KB (covers both uses)
  const int t = threadIdx.x;
  const int w = t >> 6, lane = t & 63, m16 = lane & 15, quad = lane >> 4;
  const int task = blockIdx.y;
  const int row0 = blockIdx.x * 64;
  const int b = row0 >> 8, n0 = row0 & 255;

  if (task < 11) {
    const int c = act_of(task), g = grade_of(c);
    f32x4 acc[24];
#pragma unroll
    for (int nt = 0; nt < 24; nt++) acc[nt] = (f32x4)0.f;
    const u16* ap = xv + ((size_t)c * 2048 + row0 + w * 16 + m16) * 64 + quad * 8;
    const u16* wb = WkvB + (size_t)g * 768 * 64 + (size_t)m16 * 64 + quad * 8;
#pragma unroll
    for (int ks = 0; ks < 2; ks++) {
      bf16x8 af = *(const bf16x8*)(ap + ks * 32);
#pragma unroll
      for (int nt = 0; nt < 24; nt++) {
        bf16x8 bf = *(const bf16x8*)(wb + (size_t)nt * 16 * 64 + ks * 32);
        acc[nt] = __builtin_amdgcn_mfma_f32_16x16x32_bf16(af, bf, acc[nt], 0, 0, 0);
      }
    }
#pragma unroll
    for (int nt = 0; nt < 24; nt++) {
      const int o = nt * 16 + m16;
      const float bias = (task == 0) ? bkv[o] : 0.f;
#pragma unroll
      for (int rr = 0; rr < 4; rr++)
        es[(w * 16 + quad * 4 + rr) * QSTR + o] = f2bf(acc[nt][rr] + bias);
    }
    __syncthreads();
    for (int ch = t; ch < 512; ch += 256) {
      int r = ch >> 3, h = ch & 7;
      const uint4* sr = (const uint4*)&es[r * QSTR + h * 48];
      u16* dst = ksel + ((size_t)(b * 8 + h) * NK + n0 + r) * KD + task * 48;
#pragma unroll
      for (int j = 0; j < 6; j++) ((uint4*)dst)[j] = sr[j];
      if (task == 10) {
        uint4 z = {0u, 0u, 0u, 0u};
        ((uint4*)dst)[6] = z;
        ((uint4*)dst)[7] = z;
      }
    }
  } else {
    const int c = task - 11, g = grade_of(c);
    f32x4 acc[24];
#pragma unroll
    for (int nt = 0; nt < 24; nt++) acc[nt] = (f32x4)0.f;
    const u16* ap = xv + ((size_t)c * 2048 + row0 + w * 16 + m16) * 64 + quad * 8;
    const u16* wb = WkvB + (size_t)g * 768 * 64 + (size_t)(384 + m16) * 64 + quad * 8;
#pragma unroll
    for (int ks = 0; ks < 2; ks++) {
      bf16x8 af = *(const bf16x8*)(ap + ks * 32);
#pragma unroll
      for (int nt = 0; nt < 24; nt++) {
        bf16x8 bf = *(const bf16x8*)(wb + (size_t)nt * 16 * 64 + ks * 32);
        acc[nt] = __builtin_amdgcn_mfma_f32_16x16x32_bf16(af, bf, acc[nt], 0, 0, 0);
      }
    }
#pragma unroll
    for (int nt = 0; nt < 24; nt++) {
      const int o = nt * 16 + m16;
      const float bias = (c == 0) ? bkv[384 + o] : 0.f;
#pragma unroll
      for (int rr = 0; rr < 4; rr++)
        es[o * VSTR + w * 16 + quad * 4 + rr] = f2bf(acc[nt][rr] + bias);
    }
    __syncthreads();
    for (int id = t; id < 6144; id += 256) {
      int o = id >> 4, part = id & 15;
      uint2 v = *(const uint2*)&es[o * VSTR + part * 4];
      int h = o / 48, oc = o - h * 48;
      *(uint2*)(vT + ((size_t)(b * 8 + h) * 768 + oc * 16 + c) * 256 + n0 + part * 4) = v;
    }
  }
}

// ---------------------------------------------------------------------------
// k2_kernel: kbias[bh*256+key] = -softplus(daa[h])/48 * sum(point k^2).
// Point slice is contiguous in ksel at [384,528).
// ---------------------------------------------------------------------------
__global__ __launch_bounds__(256) void k2_kernel(const u16* __restrict__ ksel,
                                                 const float* __restrict__ daa,
                                                 float* __restrict__ kbias) {
  int id = blockIdx.x * 256 + threadIdx.x;  // bh*256+key, < 16384
  const uint4* p = (const uint4*)(ksel + (size_t)id * KD + 384);
  float s = 0.f;
#pragma unroll
  for (int j = 0; j < 18; j++) {
    uint4 v = p[j];
    u32 a[4] = {v.x, v.y, v.z, v.w};
#pragma unroll
    for (int q = 0; q < 4; q++) {
      float lo = bf2f((u16)(a[q] & 0xFFFFu));
      float hi = bf2f((u16)(a[q] >> 16));
      s += lo * lo + hi * hi;
    }
  }
  int h = (id >> 8) & 7;
  kbias[id] = -(softplusf(daa[h]) * (1.f / 48.f)) * s;
}

// ---------------------------------------------------------------------------
// MFMA attention v9 (LDS diet -> 3 blocks/CU; single variable vs v8):
//  * Achieved-BW-bound at 2.34 TB/s (29%): in-flight requests scale achieved
//    BW, and occupancy is the cheapest in-flight multiplier.  v7 proved the
//    L2-thrash cliff at 4 blocks/CU (32-row); 3 blocks (12 waves) untested.
//  * LDS 56.3 -> 52.0 KB: staging stride 26 -> 25 u32 (25 coprime 32 ->
//    conflict-free), wred unioned onto kb (extra barrier after kbr load).
//  * Everything else identical to v8 (QBLK=64, 3D grid, ctxJ[c][row][384],
//    in-register softmax, QK^T 1-deep prefetch, 96B-burst epilogue).
// ---------------------------------------------------------------------------
#define SPBW 268
#define STGW 25
__global__ __launch_bounds__(256, 2) void attn_kernel(
    const u16* __restrict__ qsel, const u16* __restrict__ ksel,
    const float* __restrict__ kbias, const u16* __restrict__ vT,
    u16* __restrict__ ctxJ) {
  const int qt = blockIdx.x, h = blockIdx.y, b = blockIdx.z;
  const int g = b * 8 + h;

  const int t = threadIdx.x;
  const int w = t >> 6;
  const int lane = t & 63;
  const int m16 = lane & 15;
  const int quad = lane >> 4;

  // union: P (bf16, 64x268 = 34.3KB) then output staging (51.2KB)
  __shared__ __align__(16) u32 uni_s[12800];
  u16* spb = (u16*)uni_s;
  u32* stg = uni_s;
  __shared__ __align__(16) float kbw[256];   // kbias load, then wred union
  __shared__ __align__(16) float wsum[64][4];
  float (*wred)[4] = (float(*)[4])kbw;

  const size_t bh = (size_t)g;
  const int n0 = qt * 64;
  const u16* qg = qsel + (bh * NQ + n0) * KD;
  const u16* kg = ksel + bh * NK * KD;
  const u16* vg = vT + bh * 768 * 256;

  kbw[t] = kbias[bh * NK + t];
  __syncthreads();
  float kbr[4];
#pragma unroll
  for (int nt = 0; nt < 4; nt++) kbr[nt] = kbw[w * 64 + nt * 16 + m16];
  __syncthreads();  // all kbw reads done before wred (aliased) writes

  f32x4 sacc[4][4];
#pragma unroll
  for (int mt = 0; mt < 4; mt++)
#pragma unroll
    for (int nt = 0; nt < 4; nt++) sacc[mt][nt] = (f32x4)0.f;

  // ---- QK^T: 17 K-steps, 1-deep register prefetch, 16 MFMA / 8 loads ----
  const u16* qp0 = qg + (size_t)m16 * KD + quad * 8;
  const u16* qp1 = qg + (size_t)(16 + m16) * KD + quad * 8;
  const u16* qp2 = qg + (size_t)(32 + m16) * KD + quad * 8;
  const u16* qp3 = qg + (size_t)(48 + m16) * KD + quad * 8;
  const u16* kp = kg + (size_t)(w * 64 + m16) * KD + quad * 8;
  bf16x8 cq0 = *(const bf16x8*)qp0;
  bf16x8 cq1 = *(const bf16x8*)qp1;
  bf16x8 cq2 = *(const bf16x8*)qp2;
  bf16x8 cq3 = *(const bf16x8*)qp3;
  bf16x8 ck0 = *(const bf16x8*)(kp);
  bf16x8 ck1 = *(const bf16x8*)(kp + 16 * KD);
  bf16x8 ck2 = *(const bf16x8*)(kp + 32 * KD);
  bf16x8 ck3 = *(const bf16x8*)(kp + 48 * KD);
  for (int ks = 0; ks < 16; ks++) {
    const int o = (ks + 1) * 32;
    bf16x8 nq0 = *(const bf16x8*)(qp0 + o);
    bf16x8 nq1 = *(const bf16x8*)(qp1 + o);
    bf16x8 nq2 = *(const bf16x8*)(qp2 + o);
    bf16x8 nq3 = *(const bf16x8*)(qp3 + o);
    bf16x8 nk0 = *(const bf16x8*)(kp + o);
    bf16x8 nk1 = *(const bf16x8*)(kp + 16 * KD + o);
    bf16x8 nk2 = *(const bf16x8*)(kp + 32 * KD + o);
    bf16x8 nk3 = *(const bf16x8*)(kp + 48 * KD + o);
    sacc[0][0] = __builtin_amdgcn_mfma_f32_16x16x32_bf16(cq0, ck0, sacc[0][0], 0, 0, 0);
    sacc[1][0] = __builtin_amdgcn_mfma_f32_16x16x32_bf16(cq1, ck0, sacc[1][0], 0, 0, 0);
    sacc[2][0] = __builtin_amdgcn_mfma_f32_16x16x32_bf16(cq2, ck0, sacc[2][0], 0, 0, 0);
    sacc[3][0] = __builtin_amdgcn_mfma_f32_16x16x32_bf16(cq3, ck0, sacc[3][0], 0, 0, 0);
    sacc[0][1] = __builtin_amdgcn_mfma_f32_16x16x32_bf16(cq0, ck1, sacc[0][1], 0, 0, 0);
    sacc[1][1] = __builtin_amdgcn_mfma_f32_16x16x32_bf16(cq1, ck1, sacc[1][1], 0, 0, 0);
    sacc[2][1] = __builtin_amdgcn_mfma_f32_16x16x32_bf16(cq2, ck1, sacc[2][1], 0, 0, 0);
    sacc[3][1] = __builtin_amdgcn_mfma_f32_16x16x32_bf16(cq3, ck1, sacc[3][1], 0, 0, 0);
    sacc[0][2] = __builtin_amdgcn_mfma_f32_16x16x32_bf16(cq0, ck2, sacc[0][2], 0, 0, 0);
    sacc[1][2] = __builtin_amdgcn_mfma_f32_16x16x32_bf16(cq1, ck2, sacc[1][2], 0, 0, 0);
    sacc[2][2] = __builtin_amdgcn_mfma_f32_16x16x32_bf16(cq2, ck2, sacc[2][2], 0, 0, 0);
    sacc[3][2] = __builtin_amdgcn_mfma_f32_16x16x32_bf16(cq3, ck2, sacc[3][2], 0, 0, 0);
    sacc[0][3] = __builtin_amdgcn_mfma_f32_16x16x32_bf16(cq0, ck3, sacc[0][3], 0, 0, 0);
    sacc[1][3] = __builtin_amdgcn_mfma_f32_16x16x32_bf16(cq1, ck3, sacc[1][3], 0, 0, 0);
    sacc[2][3] = __builtin_amdgcn_mfma_f32_16x16x32_bf16(cq2, ck3, sacc[2][3], 0, 0, 0);
    sacc[3][3] = __builtin_amdgcn_mfma_f32_16x16x32_bf16(cq3, ck3, sacc[3][3], 0, 0, 0);
    cq0 = nq0; cq1 = nq1; cq2 = nq2; cq3 = nq3;
    ck0 = nk0; ck1 = nk1; ck2 = nk2; ck3 = nk3;
  }
  // tail K-step (ks = 16)
  sacc[0][0] = __builtin_amdgcn_mfma_f32_16x16x32_bf16(cq0, ck0, sacc[0][0], 0, 0, 0);
  sacc[1][0] = __builtin_amdgcn_mfma_f32_16x16x32_bf16(cq1, ck0, sacc[1][0], 0, 0, 0);
  sacc[2][0] = __builtin_amdgcn_mfma_f32_16x16x32_bf16(cq2, ck0, sacc[2][0], 0, 0, 0);
  sacc[3][0] = __builtin_amdgcn_mfma_f32_16x16x32_bf16(cq3, ck0, sacc[3][0], 0, 0, 0);
  sacc[0][1] = __builtin_amdgcn_mfma_f32_16x16x32_bf16(cq0, ck1, sacc[0][1], 0, 0, 0);
  sacc[1][1] = __builtin_amdgcn_mfma_f32_16x16x32_bf16(cq1, ck1, sacc[1][1], 0, 0, 0);
  sacc[2][1] = __builtin_amdgcn_mfma_f32_16x16x32_bf16(cq2, ck1, sacc[2][1], 0, 0, 0);
  sacc[3][1] = __builtin_amdgcn_mfma_f32_16x16x32_bf16(cq3, ck1, sacc[3][1], 0, 0, 0);
  sacc[0][2] = __builtin_amdgcn_mfma_f32_16x16x32_bf16(cq0, ck2, sacc[0][2], 0, 0, 0);
  sacc[1][2] = __builtin_amdgcn_mfma_f32_16x16x32_bf16(cq1, ck2, sacc[1][2], 0, 0, 0);
  sacc[2][2] = __builtin_amdgcn_mfma_f32_16x16x32_bf16(cq2, ck2, sacc[2][2], 0, 0, 0);
  sacc[3][2] = __builtin_amdgcn_mfma_f32_16x16x32_bf16(cq3, ck2, sacc[3][2], 0, 0, 0);
  sacc[0][3] = __builtin_amdgcn_mfma_f32_16x16x32_bf16(cq0, ck3, sacc[0][3], 0, 0, 0);
  sacc[1][3] = __builtin_amdgcn_mfma_f32_16x16x32_bf16(cq1, ck3, sacc[1][3], 0, 0, 0);
  sacc[2][3] = __builtin_amdgcn_mfma_f32_16x16x32_bf16(cq2, ck3, sacc[2][3], 0, 0, 0);
  sacc[3][3] = __builtin_amdgcn_mfma_f32_16x16x32_bf16(cq3, ck3, sacc[3][3], 0, 0, 0);

  // ---- softmax, in-register ----
  // lane holds score[row = mt*16+quad*4+rr][key = w*64+nt*16+m16]
#pragma unroll
  for (int mt = 0; mt < 4; mt++)
#pragma unroll
    for (int rr = 0; rr < 4; rr++) {
      float a0 = sacc[mt][0][rr] + kbr[0];
      float a1 = sacc[mt][1][rr] + kbr[1];
      float a2 = sacc[mt][2][rr] + kbr[2];
      float a3 = sacc[mt][3][rr] + kbr[3];
      sacc[mt][0][rr] = a0; sacc[mt][1][rr] = a1;
      sacc[mt][2][rr] = a2; sacc[mt][3][rr] = a3;
      float m = fmaxf(fmaxf(a0, a1), fmaxf(a2, a3));
#pragma unroll
      for (int off = 1; off < 16; off <<= 1)
        m = fmaxf(m, __shfl_xor(m, off));
      if (m16 == mt * 4 + rr) wred[mt * 16 + quad * 4 + rr][w] = m;
    }
  __syncthreads();
#pragma unroll
  for (int mt = 0; mt < 4; mt++)
#pragma unroll
    for (int rr = 0; rr < 4; rr++) {
      const int row = mt * 16 + quad * 4 + rr;
      float4 m4 = *(const float4*)wred[row];
      const float gm = fmaxf(fmaxf(m4.x, m4.y), fmaxf(m4.z, m4.w));
      float s = 0.f;
#pragma unroll
      for (int nt = 0; nt < 4; nt++) {
        float e = __expf(sacc[mt][nt][rr] - gm);
        s += e;
        spb[row * SPBW + w * 64 + nt * 16 + m16] = f2bf(e);
      }
#pragma unroll
      for (int off = 1; off < 16; off <<= 1)
        s += __shfl_xor(s, off);
      if (m16 == mt * 4 + rr) wsum[row][w] = s;
    }
  __syncthreads();

  // ---- PV: D[m=q-row][n=d], d = (oc=w*12+nt)*16 + (c=m16) ----
  f32x4 oacc[4][12];
#pragma unroll
  for (int mt = 0; mt < 4; mt++)
#pragma unroll
    for (int nt = 0; nt < 12; nt++) oacc[mt][nt] = (f32x4)0.f;

  for (int ks = 0; ks < 8; ks++) {
    bf16x8 pa0 = *(const bf16x8*)(&spb[(size_t)m16 * SPBW + ks * 32 + quad * 8]);
    bf16x8 pa1 = *(const bf16x8*)(&spb[(size_t)(16 + m16) * SPBW + ks * 32 + quad * 8]);
    bf16x8 pa2 = *(const bf16x8*)(&spb[(size_t)(32 + m16) * SPBW + ks * 32 + quad * 8]);
    bf16x8 pa3 = *(const bf16x8*)(&spb[(size_t)(48 + m16) * SPBW + ks * 32 + quad * 8]);
#pragma unroll
    for (int nt = 0; nt < 12; nt++) {
      const int d = w * 192 + nt * 16 + m16;
      bf16x8 vf = *(const bf16x8*)(vg + (size_t)d * 256 + ks * 32 + quad * 8);
      oacc[0][nt] = __builtin_amdgcn_mfma_f32_16x16x32_bf16(pa0, vf, oacc[0][nt], 0, 0, 0);
      oacc[1][nt] = __builtin_amdgcn_mfma_f32_16x16x32_bf16(pa1, vf, oacc[1][nt], 0, 0, 0);
      oacc[2][nt] = __builtin_amdgcn_mfma_f32_16x16x32_bf16(pa2, vf, oacc[2][nt], 0, 0, 0);
      oacc[3][nt] = __builtin_amdgcn_mfma_f32_16x16x32_bf16(pa3, vf, oacc[3][nt], 0, 0, 0);
    }
  }

  // ---- staged epilogue: 2 chunks of 8 c; full 96B runs per thread ----
  // ctxJ layout: [c][row][384], this block's slice at h*48.
  const size_t rowbase = (size_t)b * NQ + n0;
#pragma unroll
  for (int ch2 = 0; ch2 < 2; ch2++) {
    __syncthreads();  // protect union (P reads / previous chunk reads done)
    if ((m16 >> 3) == ch2) {
      const int c8 = m16 & 7;
#pragma unroll
      for (int mt = 0; mt < 4; mt++)
#pragma unroll
        for (int rr = 0; rr < 4; rr++) {
          const int row = mt * 16 + quad * 4 + rr;
          float4 s4 = *(const float4*)wsum[row];
          const float iv = 1.f / (s4.x + s4.y + s4.z + s4.w);
          u32* dp = stg + (row * 8 + c8) * STGW + w * 6;
#pragma unroll
          for (int j = 0; j < 6; j++) {
            u32 lo = f2bf(oacc[mt][2 * j][rr] * iv);
            u32 hi = f2bf(oacc[mt][2 * j + 1][rr] * iv);
            dp[j] = lo | (hi << 16);
          }
        }
    }
    __syncthreads();
    // write one full 96B run per thread: 6x dwordx4, contiguous (512 runs)
    for (int ch = t; ch < 512; ch += 256) {
      const int prow = ch >> 3, pc8 = ch & 7;
      const u32* sp2 = stg + (prow * 8 + pc8) * STGW;
      u16* dst = ctxJ + ((size_t)(ch2 * 8 + pc8) * 8192 + rowbase + prow) * 384 + h * 48;
#pragma unroll
      for (int j6 = 0; j6 < 6; j6++) {
        uint2 a = *(const uint2*)(sp2 + j6 * 4);
        uint2 bb2 = *(const uint2*)(sp2 + j6 * 4 + 2);
        uint4 v4v = {a.x, a.y, bb2.x, bb2.y};
        *(uint4*)(dst + j6 * 8) = v4v;
      }
    }
  }
}

// ---------------------------------------------------------------------------
// out_kernel v4 (baseline-proven): block 1024 = 16 waves (wave = component).
// ctxJ [c][row][384], K=384.
// ---------------------------------------------------------------------------
#define ESTR2 785
__global__ __launch_bounds__(1024) void out_kernel(
    const u16* __restrict__ ctxJ, const u16* __restrict__ WoB,
    const float* __restrict__ bo, const float* __restrict__ hidden,
    float* __restrict__ out) {
  __shared__ __align__(16) float es[16 * ESTR2];  // 50.2 KB
  const int t = threadIdx.x;
  const int c = __builtin_amdgcn_readfirstlane(t >> 6);
  const int lane = t & 63;
  const int m16 = lane & 15, quad = lane >> 4;
  const int row0 = blockIdx.x * 32;
  const int g = grade_of(c);
  const u16* wb = WoB + (size_t)g * 48 * 384;

  for (int ch = 0; ch < 2; ch++) {
    const int r0 = row0 + ch * 16;
    f32x4 acc[3];
#pragma unroll
    for (int nt = 0; nt < 3; nt++) acc[nt] = (f32x4)0.f;
    const u16* ap = ctxJ + ((size_t)c * 8192 + r0 + m16) * 384 + quad * 8;
#pragma unroll 4
    for (int ks = 0; ks < 12; ks++) {
      bf16x8 af = *(const bf16x8*)(ap + ks * 32);
#pragma unroll
      for (int nt = 0; nt < 3; nt++) {
        bf16x8 bf = *(const bf16x8*)(wb + (size_t)(nt * 16 + m16) * 384 + ks * 32 + quad * 8);
        acc[nt] = __builtin_amdgcn_mfma_f32_16x16x32_bf16(af, bf, acc[nt], 0, 0, 0);
      }
    }
    __syncthreads();
#pragma unroll
    for (int nt = 0; nt < 3; nt++)
#pragma unroll
      for (int rr = 0; rr < 4; rr++)
        es[(quad * 4 + rr) * ESTR2 + c * 49 + nt * 16 + m16] = acc[nt][rr];
    __syncthreads();
#pragma unroll
    for (int k = 0; k < 3; k++) {
      int m4 = t + 1024 * k;
      int r = m4 / 192;
      int col0 = (m4 - r * 192) * 4;
      int o = col0 >> 4, cb = col0 & 15;
      const float* er = &es[r * ESTR2 + o];
      float4 v;
      v.x = er[(cb + 0) * 49];
      v.y = er[(cb + 1) * 49];
      v.z = er[(cb + 2) * 49];
      v.w = er[(cb + 3) * 49];
      if (cb == 0) v.x += bo[o];
      size_t gidx = (size_t)(r0 + r) * 768 + col0;
      const float4 hv = *(const float4*)&hidden[gidx];
      v.x += hv.x; v.y += hv.y; v.z += hv.z; v.w += hv.w;
      *(float4*)&out[gidx] = v;
    }
  }
}

// ---------------------------------------------------------------------------
extern "C" void kernel_launch(void* const* d_in, const int* in_sizes, int n_in,
                              void* d_out, int out_size, void* d_ws, size_t ws_size,
                              hipStream_t stream) {
  const float* hidden = (const float*)d_in[0];
  const float* vis = (const float*)d_in[1];
  const float* lnw = (const float*)d_in[2];
  const float* Wq = (const float*)d_in[3];
  const float* bq = (const float*)d_in[4];
  const float* Wkv = (const float*)d_in[5];
  const float* bkv = (const float*)d_in[6];
  const float* Wo = (const float*)d_in[7];
  const float* bo = (const float*)d_in[8];
  const float* daa = (const float*)d_in[9];
  float* out = (float*)d_out;

  char* ws = (char*)d_ws;
  size_t off = 0;
  auto carve = [&](size_t bytes) -> void* {
    void* p = ws + off;
    off += (bytes + 255) & ~(size_t)255;
    return p;
  };
  float* rscale = (float*)carve((size_t)BB * NQ * 4);
  u16* WqB = (u16*)carve((size_t)5 * 384 * 64 * 2);
  u16* WkvB = (u16*)carve((size_t)5 * 768 * 64 * 2);
  u16* WoB = (u16*)carve((size_t)5 * 48 * 384 * 2);
  u16* qsel = (u16*)carve((size_t)BB * HH * NQ * KD * 2);
  u16* ksel = (u16*)carve((size_t)BB * HH * NK * KD * 2);
  u16* vT = (u16*)carve((size_t)BB * HH * 768 * 256 * 2);
  float* kbias = (float*)carve((size_t)BB * HH * NK * 4);
  // union: [xq | xv] consumed by q/kv, then ctxJ ([c][row][384]) overwrites
  char* uni = (char*)carve((size_t)16 * 384 * 8192 * 2);
  u16* ctxJ = (u16*)uni;
  u16* xq = (u16*)uni;                                      // 16 MB
  u16* xv = (u16*)(uni + (size_t)16 * 8192 * 64 * 2);       // 4 MB

  rms_kernel<<<BB * NQ / 32, 256, 0, stream>>>(hidden, rscale);
  wB_kernel<<<1800, 256, 0, stream>>>(Wq, Wkv, Wo, WqB, WkvB, WoB);
  xJ_kernel<<<BB * NQ / 64, 256, 0, stream>>>(hidden, xq, rscale, lnw, BB * NQ, 1);
  xJ_kernel<<<BB * NK / 64, 256, 0, stream>>>(vis, xv, nullptr, nullptr, BB * NK, 0);
  kv_mfma<<<dim3(BB * NK / 64, 27), 256, 0, stream>>>(xv, WkvB, bkv, ksel, vT);
  k2_kernel<<<64, 256, 0, stream>>>(ksel, daa, kbias);
  q_mfma<<<dim3(BB * NQ / 64, 11), 256, 0, stream>>>(xq, WqB, bq, daa, qsel);
  attn_kernel<<<dim3(NQ / 64, HH, BB), 256, 0, stream>>>(qsel, ksel, kbias, vT, ctxJ);
  out_kernel<<<256, 1024, 0, stream>>>(ctxJ, WoB, bo, hidden, out);
}

// Round 11
// 446.163 us; speedup vs baseline: 1.3040x; 1.3040x over previous
//
#include <hip/hip_runtime.h>

typedef unsigned short u16;
typedef unsigned int u32;
typedef unsigned long long u64;

typedef float f32x4 __attribute__((ext_vector_type(4)));
typedef short bf16x8 __attribute__((ext_vector_type(8)));

#define BB 8
#define NQ 1024
#define NK 256
#define HH 8
#define KD 544   // padded score-dot length (11*48=528 -> 544 = 17*32)

__device__ __forceinline__ float bf2f(u16 u) {
  union { u32 i; float f; } v; v.i = ((u32)u) << 16; return v.f;
}
__device__ __forceinline__ u16 f2bf(float f) {
  union { u32 i; float f; } v; v.f = f;
  u32 i = v.i;
  return (u16)((i + 0x7FFFu + ((i >> 16) & 1u)) >> 16);
}
__device__ __forceinline__ float softplusf(float d) {
  return (d > 20.f) ? d : log1pf(__expf(d));
}

// grade per component c (GRADE_IDX), nibble-packed
#define GRADE_TAB 0x4333322222211110ULL
// active component for score-slot s (slots 0..10 = INNER(8) then POINT(3))
#define ACT_TAB   0xDCBEA984320ULL
__device__ __forceinline__ int grade_of(int c) { return (int)((GRADE_TAB >> (c * 4)) & 15ULL); }
__device__ __forceinline__ int act_of(int s) { return (int)((ACT_TAB >> (s * 4)) & 15ULL); }

constexpr float INV_S384 = 0.05103103630798288f; // 1/sqrt(8*48)

// ---------------------------------------------------------------------------
// rms_kernel: rscale[row] = rsqrt(mean_i sum_c x^2 /48 + eps). 32 rows/block.
// ---------------------------------------------------------------------------
__global__ __launch_bounds__(256) void rms_kernel(const float* __restrict__ hidden,
                                                  float* __restrict__ rscale) {
  const int t = threadIdx.x;
  const int row = blockIdx.x * 32 + (t >> 3);
  const int l = t & 7;
  const float4* src = (const float4*)(hidden + (size_t)row * 768);
  float s = 0.f;
#pragma unroll
  for (int k = 0; k < 24; k++) {
    float4 v = src[l + 8 * k];
    s += v.x * v.x + v.y * v.y + v.z * v.z + v.w * v.w;
  }
#pragma unroll
  for (int off = 4; off; off >>= 1) s += __shfl_xor(s, off, 8);
  if (l == 0) rscale[row] = rsqrtf(s * (1.f / 48.f) + 1e-6f);
}

// ---------------------------------------------------------------------------
// wB_kernel: WqB[g][o][64] / WkvB[g][o][64] bf16 (K padded 48->64, zeros) for
// MFMA B-frags; WoB = bf16(Wo) (K=384 layout, unchanged).
// ---------------------------------------------------------------------------
__global__ __launch_bounds__(256) void wB_kernel(
    const float* __restrict__ Wq, const float* __restrict__ Wkv,
    const float* __restrict__ Wo, u16* __restrict__ WqB,
    u16* __restrict__ WkvB, u16* __restrict__ WoB) {
  int idx = blockIdx.x * 256 + threadIdx.x;
  const int NA = 5 * 384 * 64, NB = 5 * 768 * 64, NC = 5 * 48 * 384;
  if (idx < NA) {
    int g = idx / (384 * 64);
    int rem = idx - g * 384 * 64;
    int o = rem >> 6, j = rem & 63;
    WqB[idx] = (j < 48) ? f2bf(Wq[((size_t)g * 384 + o) * 48 + j]) : (u16)0;
  } else if (idx < NA + NB) {
    int k = idx - NA;
    int g = k / (768 * 64);
    int rem = k - g * 768 * 64;
    int o = rem >> 6, j = rem & 63;
    WkvB[k] = (j < 48) ? f2bf(Wkv[((size_t)g * 768 + o) * 48 + j]) : (u16)0;
  } else if (idx < NA + NB + NC) {
    int k = idx - NA - NB;
    WoB[k] = f2bf(Wo[k]);
  }
}

// ---------------------------------------------------------------------------
// xJ_kernel: x[row][i*16+c] (f32) -> xJ[c][row][64] bf16 (48 real i + 16 zero
// pad), optional RMS*lnw fold.  block = 64 rows via 4 chunks of 16.
// ---------------------------------------------------------------------------
__global__ __launch_bounds__(256) void xJ_kernel(
    const float* __restrict__ src, u16* __restrict__ dst,
    const float* __restrict__ rscale, const float* __restrict__ lnw,
    int NR, int norm) {
  __shared__ __align__(16) float ls[16 * 772];
  __shared__ float rs_s[16];
  const int t = threadIdx.x;
  const int row0 = blockIdx.x * 64;
  const int row16 = t & 15, c = t >> 4;
  for (int chunk = 0; chunk < 4; chunk++) {
    const int r0c = row0 + chunk * 16;
    __syncthreads();
    if (t < 16) rs_s[t] = norm ? rscale[r0c + t] : 1.f;
#pragma unroll
    for (int k = 0; k < 12; k++) {
      int f = t + 256 * k;
      int r = f / 192, j = f - r * 192;
      *(float4*)&ls[r * 772 + j * 4] =
          *(const float4*)(src + (size_t)(r0c + r) * 768 + j * 4);
    }
    __syncthreads();
    const float rsv = rs_s[row16];
    u16 buf[64];
#pragma unroll
    for (int i = 0; i < 48; i++) {
      float v = ls[row16 * 772 + i * 16 + c];
      if (norm) v *= rsv * lnw[i];
      buf[i] = f2bf(v);
    }
#pragma unroll
    for (int i = 48; i < 64; i++) buf[i] = 0;
    u16* dp = dst + ((size_t)c * NR + r0c + row16) * 64;
#pragma unroll
    for (int j4 = 0; j4 < 8; j4++) *(uint4*)(dp + j4 * 8) = *(uint4*)&buf[j4 * 8];
  }
}

// ---------------------------------------------------------------------------
// q_mfma: grid (128 rowblks of 64, 11 slots).  D[64 rows][384 o] = xq[c] (A)
// x WqB[g] (B), K=64.  Epilogue: scale(+bias) -> LDS -> 96B row-chunk stores
// into qsel (slot-10 blocks also zero the [528,544) pad).
// ---------------------------------------------------------------------------
#define QSTR 392
__global__ __launch_bounds__(256) void q_mfma(
    const u16* __restrict__ xq, const u16* __restrict__ WqB,
    const float* __restrict__ bq, const float* __restrict__ daa,
    u16* __restrict__ qsel) {
  __shared__ __align__(16) u16 es[4 * 16 * QSTR];  // 50.2 KB
  const int t = threadIdx.x;
  const int w = t >> 6, lane = t & 63, m16 = lane & 15, quad = lane >> 4;
  const int slot = blockIdx.y;
  const int c = act_of(slot), g = grade_of(c);
  const int row0 = blockIdx.x * 64;
  const int b = row0 >> 10, n0 = row0 & 1023;
  f32x4 acc[24];
#pragma unroll
  for (int nt = 0; nt < 24; nt++) acc[nt] = (f32x4)0.f;
  const u16* ap = xq + ((size_t)c * 8192 + row0 + w * 16 + m16) * 64 + quad * 8;
  const u16* wb = WqB + (size_t)g * 384 * 64 + (size_t)m16 * 64 + quad * 8;
#pragma unroll
  for (int ks = 0; ks < 2; ks++) {
    bf16x8 af = *(const bf16x8*)(ap + ks * 32);
#pragma unroll
    for (int nt = 0; nt < 24; nt++) {
      bf16x8 bf = *(const bf16x8*)(wb + (size_t)nt * 16 * 64 + ks * 32);
      acc[nt] = __builtin_amdgcn_mfma_f32_16x16x32_bf16(af, bf, acc[nt], 0, 0, 0);
    }
  }
#pragma unroll
  for (int nt = 0; nt < 24; nt++) {
    const int o = nt * 16 + m16;
    const int h = o / 48;
    const float sc = (slot < 8) ? INV_S384 : (2.f * softplusf(daa[h]) * (1.f / 48.f));
    const float bias = (slot == 0) ? bq[o] : 0.f;
#pragma unroll
    for (int rr = 0; rr < 4; rr++)
      es[(w * 16 + quad * 4 + rr) * QSTR + o] = f2bf((acc[nt][rr] + bias) * sc);
  }
  __syncthreads();
  for (int ch = t; ch < 512; ch += 256) {
    int r = ch >> 3, h = ch & 7;
    const uint4* sr = (const uint4*)&es[r * QSTR + h * 48];
    u16* dst = qsel + ((size_t)(b * 8 + h) * NQ + n0 + r) * KD + slot * 48;
#pragma unroll
    for (int j = 0; j < 6; j++) ((uint4*)dst)[j] = sr[j];
    if (slot == 10) {
      uint4 z = {0u, 0u, 0u, 0u};
      ((uint4*)dst)[6] = z;  // [528,536)
      ((uint4*)dst)[7] = z;  // [536,544)
    }
  }
}

// ---------------------------------------------------------------------------
// kv_mfma: grid (32 keyblks of 64, 27 tasks).  task<11: k-slot -> ksel (same
// structure as q_mfma, no scale).  task>=11: v component c=task-11 -> vT via
// [o][key] LDS staging (stride 72) and 8B key-contiguous stores.
// ---------------------------------------------------------------------------
#define VSTR 72
__global__ __launch_bounds__(256) void kv_mfma(
    const u16* __restrict__ xv, const u16* __restrict__ WkvB,
    const float* __restrict__ bkv, u16* __restrict__ ksel,
    u16* __restrict__ vT) {
  __shared__ __align__(16) u16 es[384 * VSTR];  // 55.3 KB (covers both uses)
  const int t = threadIdx.x;
  const int w = t >> 6, lane = t & 63, m16 = lane & 15, quad = lane >> 4;
  const int task = blockIdx.y;
  const int row0 = blockIdx.x * 64;
  const int b = row0 >> 8, n0 = row0 & 255;

  if (task < 11) {
    const int c = act_of(task), g = grade_of(c);
    f32x4 acc[24];
#pragma unroll
    for (int nt = 0; nt < 24; nt++) acc[nt] = (f32x4)0.f;
    const u16* ap = xv + ((size_t)c * 2048 + row0 + w * 16 + m16) * 64 + quad * 8;
    const u16* wb = WkvB + (size_t)g * 768 * 64 + (size_t)m16 * 64 + quad * 8;
#pragma unroll
    for (int ks = 0; ks < 2; ks++) {
      bf16x8 af = *(const bf16x8*)(ap + ks * 32);
#pragma unroll
      for (int nt = 0; nt < 24; nt++) {
        bf16x8 bf = *(const bf16x8*)(wb + (size_t)nt * 16 * 64 + ks * 32);
        acc[nt] = __builtin_amdgcn_mfma_f32_16x16x32_bf16(af, bf, acc[nt], 0, 0, 0);
      }
    }
#pragma unroll
    for (int nt = 0; nt < 24; nt++) {
      const int o = nt * 16 + m16;
      const float bias = (task == 0) ? bkv[o] : 0.f;
#pragma unroll
      for (int rr = 0; rr < 4; rr++)
        es[(w * 16 + quad * 4 + rr) * QSTR + o] = f2bf(acc[nt][rr] + bias);
    }
    __syncthreads();
    for (int ch = t; ch < 512; ch += 256) {
      int r = ch >> 3, h = ch & 7;
      const uint4* sr = (const uint4*)&es[r * QSTR + h * 48];
      u16* dst = ksel + ((size_t)(b * 8 + h) * NK + n0 + r) * KD + task * 48;
#pragma unroll
      for (int j = 0; j < 6; j++) ((uint4*)dst)[j] = sr[j];
      if (task == 10) {
        uint4 z = {0u, 0u, 0u, 0u};
        ((uint4*)dst)[6] = z;
        ((uint4*)dst)[7] = z;
      }
    }
  } else {
    const int c = task - 11, g = grade_of(c);
    f32x4 acc[24];
#pragma unroll
    for (int nt = 0; nt < 24; nt++) acc[nt] = (f32x4)0.f;
    const u16* ap = xv + ((size_t)c * 2048 + row0 + w * 16 + m16) * 64 + quad * 8;
    const u16* wb = WkvB + (size_t)g * 768 * 64 + (size_t)(384 + m16) * 64 + quad * 8;
#pragma unroll
    for (int ks = 0; ks < 2; ks++) {
      bf16x8 af = *(const bf16x8*)(ap + ks * 32);
#pragma unroll
      for (int nt = 0; nt < 24; nt++) {
        bf16x8 bf = *(const bf16x8*)(wb + (size_t)nt * 16 * 64 + ks * 32);
        acc[nt] = __builtin_amdgcn_mfma_f32_16x16x32_bf16(af, bf, acc[nt], 0, 0, 0);
      }
    }
#pragma unroll
    for (int nt = 0; nt < 24; nt++) {
      const int o = nt * 16 + m16;
      const float bias = (c == 0) ? bkv[384 + o] : 0.f;
#pragma unroll
      for (int rr = 0; rr < 4; rr++)
        es[o * VSTR + w * 16 + quad * 4 + rr] = f2bf(acc[nt][rr] + bias);
    }
    __syncthreads();
    for (int id = t; id < 6144; id += 256) {
      int o = id >> 4, part = id & 15;
      uint2 v = *(const uint2*)&es[o * VSTR + part * 4];
      int h = o / 48, oc = o - h * 48;
      *(uint2*)(vT + ((size_t)(b * 8 + h) * 768 + oc * 16 + c) * 256 + n0 + part * 4) = v;
    }
  }
}

// ---------------------------------------------------------------------------
// k2_kernel: kbias[bh*256+key] = -softplus(daa[h])/48 * sum(point k^2).
// Point slice is contiguous in ksel at [384,528).
// ---------------------------------------------------------------------------
__global__ __launch_bounds__(256) void k2_kernel(const u16* __restrict__ ksel,
                                                 const float* __restrict__ daa,
                                                 float* __restrict__ kbias) {
  int id = blockIdx.x * 256 + threadIdx.x;  // bh*256+key, < 16384
  const uint4* p = (const uint4*)(ksel + (size_t)id * KD + 384);
  float s = 0.f;
#pragma unroll
  for (int j = 0; j < 18; j++) {
    uint4 v = p[j];
    u32 a[4] = {v.x, v.y, v.z, v.w};
#pragma unroll
    for (int q = 0; q < 4; q++) {
      float lo = bf2f((u16)(a[q] & 0xFFFFu));
      float hi = bf2f((u16)(a[q] >> 16));
      s += lo * lo + hi * hi;
    }
  }
  int h = (id >> 8) & 7;
  kbias[id] = -(softplusf(daa[h]) * (1.f / 48.f)) * s;
}

// ---------------------------------------------------------------------------
// MFMA attention v10 (= v8 + deeper prefetch; v9's 3-blocks/CU reverted):
//  * v9 lesson: L2-thrash cliff is at 3 blocks/CU (WRITE 133->302MB) ->
//    2 blocks/CU is the ONLY clean point.  LDS back to 56.3KB, STGW=26.
//  * QK^T 2-deep software pipeline: loads for steps s+2/s+3 in flight while
//    the 32 MFMAs of steps s/s+1 run (16 outstanding loads/wave, was 8).
//  * PV 1-deep V prefetch: V(ks+1) loads issued before MFMAs of ks (was
//    zero-distance).
// ---------------------------------------------------------------------------
#define SPBW 268
#define STGW 26

#define QK_MFMA_BLOCK(AQ0, AQ1, AQ2, AQ3, AK0, AK1, AK2, AK3)                 \
  sacc[0][0] = __builtin_amdgcn_mfma_f32_16x16x32_bf16(AQ0, AK0, sacc[0][0], 0, 0, 0); \
  sacc[1][0] = __builtin_amdgcn_mfma_f32_16x16x32_bf16(AQ1, AK0, sacc[1][0], 0, 0, 0); \
  sacc[2][0] = __builtin_amdgcn_mfma_f32_16x16x32_bf16(AQ2, AK0, sacc[2][0], 0, 0, 0); \
  sacc[3][0] = __builtin_amdgcn_mfma_f32_16x16x32_bf16(AQ3, AK0, sacc[3][0], 0, 0, 0); \
  sacc[0][1] = __builtin_amdgcn_mfma_f32_16x16x32_bf16(AQ0, AK1, sacc[0][1], 0, 0, 0); \
  sacc[1][1] = __builtin_amdgcn_mfma_f32_16x16x32_bf16(AQ1, AK1, sacc[1][1], 0, 0, 0); \
  sacc[2][1] = __builtin_amdgcn_mfma_f32_16x16x32_bf16(AQ2, AK1, sacc[2][1], 0, 0, 0); \
  sacc[3][1] = __builtin_amdgcn_mfma_f32_16x16x32_bf16(AQ3, AK1, sacc[3][1], 0, 0, 0); \
  sacc[0][2] = __builtin_amdgcn_mfma_f32_16x16x32_bf16(AQ0, AK2, sacc[0][2], 0, 0, 0); \
  sacc[1][2] = __builtin_amdgcn_mfma_f32_16x16x32_bf16(AQ1, AK2, sacc[1][2], 0, 0, 0); \
  sacc[2][2] = __builtin_amdgcn_mfma_f32_16x16x32_bf16(AQ2, AK2, sacc[2][2], 0, 0, 0); \
  sacc[3][2] = __builtin_amdgcn_mfma_f32_16x16x32_bf16(AQ3, AK2, sacc[3][2], 0, 0, 0); \
  sacc[0][3] = __builtin_amdgcn_mfma_f32_16x16x32_bf16(AQ0, AK3, sacc[0][3], 0, 0, 0); \
  sacc[1][3] = __builtin_amdgcn_mfma_f32_16x16x32_bf16(AQ1, AK3, sacc[1][3], 0, 0, 0); \
  sacc[2][3] = __builtin_amdgcn_mfma_f32_16x16x32_bf16(AQ2, AK3, sacc[2][3], 0, 0, 0); \
  sacc[3][3] = __builtin_amdgcn_mfma_f32_16x16x32_bf16(AQ3, AK3, sacc[3][3], 0, 0, 0);

__global__ __launch_bounds__(256, 2) void attn_kernel(
    const u16* __restrict__ qsel, const u16* __restrict__ ksel,
    const float* __restrict__ kbias, const u16* __restrict__ vT,
    u16* __restrict__ ctxJ) {
  const int qt = blockIdx.x, h = blockIdx.y, b = blockIdx.z;
  const int g = b * 8 + h;

  const int t = threadIdx.x;
  const int w = t >> 6;
  const int lane = t & 63;
  const int m16 = lane & 15;
  const int quad = lane >> 4;

  // union: P (bf16, 64x268 = 34.3KB) then output staging (53.2KB)
  __shared__ __align__(16) u32 uni_s[13312];
  u16* spb = (u16*)uni_s;
  u32* stg = uni_s;
  __shared__ float kb[256];
  __shared__ __align__(16) float wred[64][4];
  __shared__ __align__(16) float wsum[64][4];

  const size_t bh = (size_t)g;
  const int n0 = qt * 64;
  const u16* qg = qsel + (bh * NQ + n0) * KD;
  const u16* kg = ksel + bh * NK * KD;
  const u16* vg = vT + bh * 768 * 256;

  kb[t] = kbias[bh * NK + t];
  __syncthreads();
  float kbr[4];
#pragma unroll
  for (int nt = 0; nt < 4; nt++) kbr[nt] = kb[w * 64 + nt * 16 + m16];

  f32x4 sacc[4][4];
#pragma unroll
  for (int mt = 0; mt < 4; mt++)
#pragma unroll
    for (int nt = 0; nt < 4; nt++) sacc[mt][nt] = (f32x4)0.f;

  // ---- QK^T: 17 K-steps, 2-deep software pipeline ----
  const u16* qp0 = qg + (size_t)m16 * KD + quad * 8;
  const u16* qp1 = qg + (size_t)(16 + m16) * KD + quad * 8;
  const u16* qp2 = qg + (size_t)(32 + m16) * KD + quad * 8;
  const u16* qp3 = qg + (size_t)(48 + m16) * KD + quad * 8;
  const u16* kp = kg + (size_t)(w * 64 + m16) * KD + quad * 8;
  // c = step 0, d = step 1
  bf16x8 cq0 = *(const bf16x8*)qp0;
  bf16x8 cq1 = *(const bf16x8*)qp1;
  bf16x8 cq2 = *(const bf16x8*)qp2;
  bf16x8 cq3 = *(const bf16x8*)qp3;
  bf16x8 ck0 = *(const bf16x8*)(kp);
  bf16x8 ck1 = *(const bf16x8*)(kp + 16 * KD);
  bf16x8 ck2 = *(const bf16x8*)(kp + 32 * KD);
  bf16x8 ck3 = *(const bf16x8*)(kp + 48 * KD);
  bf16x8 dq0 = *(const bf16x8*)(qp0 + 32);
  bf16x8 dq1 = *(const bf16x8*)(qp1 + 32);
  bf16x8 dq2 = *(const bf16x8*)(qp2 + 32);
  bf16x8 dq3 = *(const bf16x8*)(qp3 + 32);
  bf16x8 dk0 = *(const bf16x8*)(kp + 32);
  bf16x8 dk1 = *(const bf16x8*)(kp + 16 * KD + 32);
  bf16x8 dk2 = *(const bf16x8*)(kp + 32 * KD + 32);
  bf16x8 dk3 = *(const bf16x8*)(kp + 48 * KD + 32);
  // loop: compute steps 2i, 2i+1; prefetch 2i+2, 2i+3 (i = 0..6 -> steps 0..13)
  for (int i = 0; i < 7; i++) {
    const int oA = (2 * i + 2) * 32;
    bf16x8 nq0 = *(const bf16x8*)(qp0 + oA);
    bf16x8 nq1 = *(const bf16x8*)(qp1 + oA);
    bf16x8 nq2 = *(const bf16x8*)(qp2 + oA);
    bf16x8 nq3 = *(const bf16x8*)(qp3 + oA);
    bf16x8 nk0 = *(const bf16x8*)(kp + oA);
    bf16x8 nk1 = *(const bf16x8*)(kp + 16 * KD + oA);
    bf16x8 nk2 = *(const bf16x8*)(kp + 32 * KD + oA);
    bf16x8 nk3 = *(const bf16x8*)(kp + 48 * KD + oA);
    const int oB = (2 * i + 3) * 32;
    bf16x8 mq0 = *(const bf16x8*)(qp0 + oB);
    bf16x8 mq1 = *(const bf16x8*)(qp1 + oB);
    bf16x8 mq2 = *(const bf16x8*)(qp2 + oB);
    bf16x8 mq3 = *(const bf16x8*)(qp3 + oB);
    bf16x8 mk0 = *(const bf16x8*)(kp + oB);
    bf16x8 mk1 = *(const bf16x8*)(kp + 16 * KD + oB);
    bf16x8 mk2 = *(const bf16x8*)(kp + 32 * KD + oB);
    bf16x8 mk3 = *(const bf16x8*)(kp + 48 * KD + oB);
    QK_MFMA_BLOCK(cq0, cq1, cq2, cq3, ck0, ck1, ck2, ck3)   // step 2i
    QK_MFMA_BLOCK(dq0, dq1, dq2, dq3, dk0, dk1, dk2, dk3)   // step 2i+1
    cq0 = nq0; cq1 = nq1; cq2 = nq2; cq3 = nq3;
    ck0 = nk0; ck1 = nk1; ck2 = nk2; ck3 = nk3;
    dq0 = mq0; dq1 = mq1; dq2 = mq2; dq3 = mq3;
    dk0 = mk0; dk1 = mk1; dk2 = mk2; dk3 = mk3;
  }
  // tail: c = step 14, d = step 15; prefetch step 16, then compute it
  {
    const int oT = 16 * 32;
    bf16x8 nq0 = *(const bf16x8*)(qp0 + oT);
    bf16x8 nq1 = *(const bf16x8*)(qp1 + oT);
    bf16x8 nq2 = *(const bf16x8*)(qp2 + oT);
    bf16x8 nq3 = *(const bf16x8*)(qp3 + oT);
    bf16x8 nk0 = *(const bf16x8*)(kp + oT);
    bf16x8 nk1 = *(const bf16x8*)(kp + 16 * KD + oT);
    bf16x8 nk2 = *(const bf16x8*)(kp + 32 * KD + oT);
    bf16x8 nk3 = *(const bf16x8*)(kp + 48 * KD + oT);
    QK_MFMA_BLOCK(cq0, cq1, cq2, cq3, ck0, ck1, ck2, ck3)   // step 14
    QK_MFMA_BLOCK(dq0, dq1, dq2, dq3, dk0, dk1, dk2, dk3)   // step 15
    QK_MFMA_BLOCK(nq0, nq1, nq2, nq3, nk0, nk1, nk2, nk3)   // step 16
  }

  // ---- softmax, in-register ----
  // lane holds score[row = mt*16+quad*4+rr][key = w*64+nt*16+m16]
#pragma unroll
  for (int mt = 0; mt < 4; mt++)
#pragma unroll
    for (int rr = 0; rr < 4; rr++) {
      float a0 = sacc[mt][0][rr] + kbr[0];
      float a1 = sacc[mt][1][rr] + kbr[1];
      float a2 = sacc[mt][2][rr] + kbr[2];
      float a3 = sacc[mt][3][rr] + kbr[3];
      sacc[mt][0][rr] = a0; sacc[mt][1][rr] = a1;
      sacc[mt][2][rr] = a2; sacc[mt][3][rr] = a3;
      float m = fmaxf(fmaxf(a0, a1), fmaxf(a2, a3));
#pragma unroll
      for (int off = 1; off < 16; off <<= 1)
        m = fmaxf(m, __shfl_xor(m, off));
      if (m16 == mt * 4 + rr) wred[mt * 16 + quad * 4 + rr][w] = m;
    }
  __syncthreads();
#pragma unroll
  for (int mt = 0; mt < 4; mt++)
#pragma unroll
    for (int rr = 0; rr < 4; rr++) {
      const int row = mt * 16 + quad * 4 + rr;
      float4 m4 = *(const float4*)wred[row];
      const float gm = fmaxf(fmaxf(m4.x, m4.y), fmaxf(m4.z, m4.w));
      float s = 0.f;
#pragma unroll
      for (int nt = 0; nt < 4; nt++) {
        float e = __expf(sacc[mt][nt][rr] - gm);
        s += e;
        spb[row * SPBW + w * 64 + nt * 16 + m16] = f2bf(e);
      }
#pragma unroll
      for (int off = 1; off < 16; off <<= 1)
        s += __shfl_xor(s, off);
      if (m16 == mt * 4 + rr) wsum[row][w] = s;
    }
  __syncthreads();

  // ---- PV: D[m=q-row][n=d]; 1-deep V prefetch ----
  f32x4 oacc[4][12];
#pragma unroll
  for (int mt = 0; mt < 4; mt++)
#pragma unroll
    for (int nt = 0; nt < 12; nt++) oacc[mt][nt] = (f32x4)0.f;

  const u16* vp = vg + (size_t)(w * 192 + m16) * 256 + quad * 8;
  bf16x8 vc[12];
#pragma unroll
  for (int nt = 0; nt < 12; nt++)
    vc[nt] = *(const bf16x8*)(vp + (size_t)nt * 16 * 256);
#pragma unroll
  for (int ks = 0; ks < 8; ks++) {
    bf16x8 vn[12];
    if (ks < 7) {
#pragma unroll
      for (int nt = 0; nt < 12; nt++)
        vn[nt] = *(const bf16x8*)(vp + (size_t)nt * 16 * 256 + (ks + 1) * 32);
    }
    bf16x8 pa0 = *(const bf16x8*)(&spb[(size_t)m16 * SPBW + ks * 32 + quad * 8]);
    bf16x8 pa1 = *(const bf16x8*)(&spb[(size_t)(16 + m16) * SPBW + ks * 32 + quad * 8]);
    bf16x8 pa2 = *(const bf16x8*)(&spb[(size_t)(32 + m16) * SPBW + ks * 32 + quad * 8]);
    bf16x8 pa3 = *(const bf16x8*)(&spb[(size_t)(48 + m16) * SPBW + ks * 32 + quad * 8]);
#pragma unroll
    for (int nt = 0; nt < 12; nt++) {
      oacc[0][nt] = __builtin_amdgcn_mfma_f32_16x16x32_bf16(pa0, vc[nt], oacc[0][nt], 0, 0, 0);
      oacc[1][nt] = __builtin_amdgcn_mfma_f32_16x16x32_bf16(pa1, vc[nt], oacc[1][nt], 0, 0, 0);
      oacc[2][nt] = __builtin_amdgcn_mfma_f32_16x16x32_bf16(pa2, vc[nt], oacc[2][nt], 0, 0, 0);
      oacc[3][nt] = __builtin_amdgcn_mfma_f32_16x16x32_bf16(pa3, vc[nt], oacc[3][nt], 0, 0, 0);
    }
    if (ks < 7) {
#pragma unroll
      for (int nt = 0; nt < 12; nt++) vc[nt] = vn[nt];
    }
  }

  // ---- staged epilogue: 2 chunks of 8 c; full 96B runs per thread ----
  // ctxJ layout: [c][row][384], this block's slice at h*48.
  const size_t rowbase = (size_t)b * NQ + n0;
#pragma unroll
  for (int ch2 = 0; ch2 < 2; ch2++) {
    __syncthreads();  // protect union (P reads / previous chunk reads done)
    if ((m16 >> 3) == ch2) {
      const int c8 = m16 & 7;
#pragma unroll
      for (int mt = 0; mt < 4; mt++)
#pragma unroll
        for (int rr = 0; rr < 4; rr++) {
          const int row = mt * 16 + quad * 4 + rr;
          float4 s4 = *(const float4*)wsum[row];
          const float iv = 1.f / (s4.x + s4.y + s4.z + s4.w);
          u32* dp = stg + (row * 8 + c8) * STGW + w * 6;
#pragma unroll
          for (int j = 0; j < 6; j++) {
            u32 lo = f2bf(oacc[mt][2 * j][rr] * iv);
            u32 hi = f2bf(oacc[mt][2 * j + 1][rr] * iv);
            dp[j] = lo | (hi << 16);
          }
        }
    }
    __syncthreads();
    // write one full 96B run per thread: 6x dwordx4, contiguous (512 runs)
    for (int ch = t; ch < 512; ch += 256) {
      const int prow = ch >> 3, pc8 = ch & 7;
      const u32* sp2 = stg + (prow * 8 + pc8) * STGW;
      u16* dst = ctxJ + ((size_t)(ch2 * 8 + pc8) * 8192 + rowbase + prow) * 384 + h * 48;
#pragma unroll
      for (int j6 = 0; j6 < 6; j6++) {
        uint2 a = *(const uint2*)(sp2 + j6 * 4);
        uint2 bb2 = *(const uint2*)(sp2 + j6 * 4 + 2);
        uint4 v4v = {a.x, a.y, bb2.x, bb2.y};
        *(uint4*)(dst + j6 * 8) = v4v;
      }
    }
  }
}

// ---------------------------------------------------------------------------
// out_kernel v4 (baseline-proven): block 1024 = 16 waves (wave = component).
// ctxJ [c][row][384], K=384.
// ---------------------------------------------------------------------------
#define ESTR2 785
__global__ __launch_bounds__(1024) void out_kernel(
    const u16* __restrict__ ctxJ, const u16* __restrict__ WoB,
    const float* __restrict__ bo, const float* __restrict__ hidden,
    float* __restrict__ out) {
  __shared__ __align__(16) float es[16 * ESTR2];  // 50.2 KB
  const int t = threadIdx.x;
  const int c = __builtin_amdgcn_readfirstlane(t >> 6);
  const int lane = t & 63;
  const int m16 = lane & 15, quad = lane >> 4;
  const int row0 = blockIdx.x * 32;
  const int g = grade_of(c);
  const u16* wb = WoB + (size_t)g * 48 * 384;

  for (int ch = 0; ch < 2; ch++) {
    const int r0 = row0 + ch * 16;
    f32x4 acc[3];
#pragma unroll
    for (int nt = 0; nt < 3; nt++) acc[nt] = (f32x4)0.f;
    const u16* ap = ctxJ + ((size_t)c * 8192 + r0 + m16) * 384 + quad * 8;
#pragma unroll 4
    for (int ks = 0; ks < 12; ks++) {
      bf16x8 af = *(const bf16x8*)(ap + ks * 32);
#pragma unroll
      for (int nt = 0; nt < 3; nt++) {
        bf16x8 bf = *(const bf16x8*)(wb + (size_t)(nt * 16 + m16) * 384 + ks * 32 + quad * 8);
        acc[nt] = __builtin_amdgcn_mfma_f32_16x16x32_bf16(af, bf, acc[nt], 0, 0, 0);
      }
    }
    __syncthreads();
#pragma unroll
    for (int nt = 0; nt < 3; nt++)
#pragma unroll
      for (int rr = 0; rr < 4; rr++)
        es[(quad * 4 + rr) * ESTR2 + c * 49 + nt * 16 + m16] = acc[nt][rr];
    __syncthreads();
#pragma unroll
    for (int k = 0; k < 3; k++) {
      int m4 = t + 1024 * k;
      int r = m4 / 192;
      int col0 = (m4 - r * 192) * 4;
      int o = col0 >> 4, cb = col0 & 15;
      const float* er = &es[r * ESTR2 + o];
      float4 v;
      v.x = er[(cb + 0) * 49];
      v.y = er[(cb + 1) * 49];
      v.z = er[(cb + 2) * 49];
      v.w = er[(cb + 3) * 49];
      if (cb == 0) v.x += bo[o];
      size_t gidx = (size_t)(r0 + r) * 768 + col0;
      const float4 hv = *(const float4*)&hidden[gidx];
      v.x += hv.x; v.y += hv.y; v.z += hv.z; v.w += hv.w;
      *(float4*)&out[gidx] = v;
    }
  }
}

// ---------------------------------------------------------------------------
extern "C" void kernel_launch(void* const* d_in, const int* in_sizes, int n_in,
                              void* d_out, int out_size, void* d_ws, size_t ws_size,
                              hipStream_t stream) {
  const float* hidden = (const float*)d_in[0];
  const float* vis = (const float*)d_in[1];
  const float* lnw = (const float*)d_in[2];
  const float* Wq = (const float*)d_in[3];
  const float* bq = (const float*)d_in[4];
  const float* Wkv = (const float*)d_in[5];
  const float* bkv = (const float*)d_in[6];
  const float* Wo = (const float*)d_in[7];
  const float* bo = (const float*)d_in[8];
  const float* daa = (const float*)d_in[9];
  float* out = (float*)d_out;

  char* ws = (char*)d_ws;
  size_t off = 0;
  auto carve = [&](size_t bytes) -> void* {
    void* p = ws + off;
    off += (bytes + 255) & ~(size_t)255;
    return p;
  };
  float* rscale = (float*)carve((size_t)BB * NQ * 4);
  u16* WqB = (u16*)carve((size_t)5 * 384 * 64 * 2);
  u16* WkvB = (u16*)carve((size_t)5 * 768 * 64 * 2);
  u16* WoB = (u16*)carve((size_t)5 * 48 * 384 * 2);
  u16* qsel = (u16*)carve((size_t)BB * HH * NQ * KD * 2);
  u16* ksel = (u16*)carve((size_t)BB * HH * NK * KD * 2);
  u16* vT = (u16*)carve((size_t)BB * HH * 768 * 256 * 2);
  float* kbias = (float*)carve((size_t)BB * HH * NK * 4);
  // union: [xq | xv] consumed by q/kv, then ctxJ ([c][row][384]) overwrites
  char* uni = (char*)carve((size_t)16 * 384 * 8192 * 2);
  u16* ctxJ = (u16*)uni;
  u16* xq = (u16*)uni;                                      // 16 MB
  u16* xv = (u16*)(uni + (size_t)16 * 8192 * 64 * 2);       // 4 MB

  rms_kernel<<<BB * NQ / 32, 256, 0, stream>>>(hidden, rscale);
  wB_kernel<<<1800, 256, 0, stream>>>(Wq, Wkv, Wo, WqB, WkvB, WoB);
  xJ_kernel<<<BB * NQ / 64, 256, 0, stream>>>(hidden, xq, rscale, lnw, BB * NQ, 1);
  xJ_kernel<<<BB * NK / 64, 256, 0, stream>>>(vis, xv, nullptr, nullptr, BB * NK, 0);
  kv_mfma<<<dim3(BB * NK / 64, 27), 256, 0, stream>>>(xv, WkvB, bkv, ksel, vT);
  k2_kernel<<<64, 256, 0, stream>>>(ksel, daa, kbias);
  q_mfma<<<dim3(BB * NQ / 64, 11), 256, 0, stream>>>(xq, WqB, bq, daa, qsel);
  attn_kernel<<<dim3(NQ / 64, HH, BB), 256, 0, stream>>>(qsel, ksel, kbias, vT, ctxJ);
  out_kernel<<<256, 1024, 0, stream>>>(ctxJ, WoB, bo, hidden, out);
}

// Round 12
// 443.533 us; speedup vs baseline: 1.3118x; 1.0059x over previous
//
#include <hip/hip_runtime.h>

typedef unsigned short u16;
typedef unsigned int u32;
typedef unsigned long long u64;

typedef float f32x4 __attribute__((ext_vector_type(4)));
typedef short bf16x8 __attribute__((ext_vector_type(8)));

#define BB 8
#define NQ 1024
#define NK 256
#define HH 8
#define KD 544   // padded score-dot length (11*48=528 -> 544 = 17*32)

__device__ __forceinline__ float bf2f(u16 u) {
  union { u32 i; float f; } v; v.i = ((u32)u) << 16; return v.f;
}
__device__ __forceinline__ u16 f2bf(float f) {
  union { u32 i; float f; } v; v.f = f;
  u32 i = v.i;
  return (u16)((i + 0x7FFFu + ((i >> 16) & 1u)) >> 16);
}
__device__ __forceinline__ float softplusf(float d) {
  return (d > 20.f) ? d : log1pf(__expf(d));
}

// grade per component c (GRADE_IDX), nibble-packed
#define GRADE_TAB 0x4333322222211110ULL
// active component for score-slot s (slots 0..10 = INNER(8) then POINT(3))
#define ACT_TAB   0xDCBEA984320ULL
__device__ __forceinline__ int grade_of(int c) { return (int)((GRADE_TAB >> (c * 4)) & 15ULL); }
__device__ __forceinline__ int act_of(int s) { return (int)((ACT_TAB >> (s * 4)) & 15ULL); }

constexpr float INV_S384 = 0.05103103630798288f; // 1/sqrt(8*48)

// ---------------------------------------------------------------------------
// wB_kernel: WqB[g][o][64] / WkvB[g][o][64] bf16 (K padded 48->64, zeros) for
// MFMA B-frags; WoB = bf16(Wo) (K=384 layout, unchanged).
// ---------------------------------------------------------------------------
__global__ __launch_bounds__(256) void wB_kernel(
    const float* __restrict__ Wq, const float* __restrict__ Wkv,
    const float* __restrict__ Wo, u16* __restrict__ WqB,
    u16* __restrict__ WkvB, u16* __restrict__ WoB) {
  int idx = blockIdx.x * 256 + threadIdx.x;
  const int NA = 5 * 384 * 64, NB = 5 * 768 * 64, NC = 5 * 48 * 384;
  if (idx < NA) {
    int g = idx / (384 * 64);
    int rem = idx - g * 384 * 64;
    int o = rem >> 6, j = rem & 63;
    WqB[idx] = (j < 48) ? f2bf(Wq[((size_t)g * 384 + o) * 48 + j]) : (u16)0;
  } else if (idx < NA + NB) {
    int k = idx - NA;
    int g = k / (768 * 64);
    int rem = k - g * 768 * 64;
    int o = rem >> 6, j = rem & 63;
    WkvB[k] = (j < 48) ? f2bf(Wkv[((size_t)g * 768 + o) * 48 + j]) : (u16)0;
  } else if (idx < NA + NB + NC) {
    int k = idx - NA - NB;
    WoB[k] = f2bf(Wo[k]);
  }
}

// ---------------------------------------------------------------------------
// xJ_kernel (rms FUSED): x[row][i*16+c] (f32) -> xJ[c][row][64] bf16 (48 real
// i + 16 zero pad).  norm=1: compute rscale in-kernel from the staged chunk
// (saves the separate rms_kernel launch + duplicate 25MB hidden read).
// block = 64 rows via 4 chunks of 16.
// ---------------------------------------------------------------------------
__global__ __launch_bounds__(256) void xJ_kernel(
    const float* __restrict__ src, u16* __restrict__ dst,
    const float* __restrict__ lnw, int NR, int norm) {
  __shared__ __align__(16) float ls[16 * 772];
  __shared__ float rs_s[16];
  const int t = threadIdx.x;
  const int row0 = blockIdx.x * 64;
  const int row16 = t & 15, c = t >> 4;
  for (int chunk = 0; chunk < 4; chunk++) {
    const int r0c = row0 + chunk * 16;
    __syncthreads();
#pragma unroll
    for (int k = 0; k < 12; k++) {
      int f = t + 256 * k;
      int r = f / 192, j = f - r * 192;
      *(float4*)&ls[r * 772 + j * 4] =
          *(const float4*)(src + (size_t)(r0c + r) * 768 + j * 4);
    }
    __syncthreads();
    if (norm) {
      // in-LDS RMS: thread (r=t>>4, j16=t&15) sums 48 elems of row r
      const int r = t >> 4, j16 = t & 15;
      float s = 0.f;
#pragma unroll
      for (int i = 0; i < 12; i++) {
        float4 v = *(const float4*)&ls[r * 772 + j16 * 48 + i * 4];
        s += v.x * v.x + v.y * v.y + v.z * v.z + v.w * v.w;
      }
#pragma unroll
      for (int off = 8; off; off >>= 1) s += __shfl_xor(s, off, 16);
      if (j16 == 0) rs_s[r] = rsqrtf(s * (1.f / 48.f) + 1e-6f);
      __syncthreads();
    }
    const float rsv = norm ? rs_s[row16] : 1.f;
    u16 buf[64];
#pragma unroll
    for (int i = 0; i < 48; i++) {
      float v = ls[row16 * 772 + i * 16 + c];
      if (norm) v *= rsv * lnw[i];
      buf[i] = f2bf(v);
    }
#pragma unroll
    for (int i = 48; i < 64; i++) buf[i] = 0;
    u16* dp = dst + ((size_t)c * NR + r0c + row16) * 64;
#pragma unroll
    for (int j4 = 0; j4 < 8; j4++) *(uint4*)(dp + j4 * 8) = *(uint4*)&buf[j4 * 8];
  }
}

// ---------------------------------------------------------------------------
// q_mfma: grid (128 rowblks of 64, 11 slots).  D[64 rows][384 o] = xq[c] (A)
// x WqB[g] (B), K=64.  Epilogue: scale(+bias) -> LDS -> 96B row-chunk stores
// into qsel (slot-10 blocks also zero the [528,544) pad).
// ---------------------------------------------------------------------------
#define QSTR 392
__global__ __launch_bounds__(256) void q_mfma(
    const u16* __restrict__ xq, const u16* __restrict__ WqB,
    const float* __restrict__ bq, const float* __restrict__ daa,
    u16* __restrict__ qsel) {
  __shared__ __align__(16) u16 es[4 * 16 * QSTR];  // 50.2 KB
  const int t = threadIdx.x;
  const int w = t >> 6, lane = t & 63, m16 = lane & 15, quad = lane >> 4;
  const int slot = blockIdx.y;
  const int c = act_of(slot), g = grade_of(c);
  const int row0 = blockIdx.x * 64;
  const int b = row0 >> 10, n0 = row0 & 1023;
  f32x4 acc[24];
#pragma unroll
  for (int nt = 0; nt < 24; nt++) acc[nt] = (f32x4)0.f;
  const u16* ap = xq + ((size_t)c * 8192 + row0 + w * 16 + m16) * 64 + quad * 8;
  const u16* wb = WqB + (size_t)g * 384 * 64 + (size_t)m16 * 64 + quad * 8;
#pragma unroll
  for (int ks = 0; ks < 2; ks++) {
    bf16x8 af = *(const bf16x8*)(ap + ks * 32);
#pragma unroll
    for (int nt = 0; nt < 24; nt++) {
      bf16x8 bf = *(const bf16x8*)(wb + (size_t)nt * 16 * 64 + ks * 32);
      acc[nt] = __builtin_amdgcn_mfma_f32_16x16x32_bf16(af, bf, acc[nt], 0, 0, 0);
    }
  }
#pragma unroll
  for (int nt = 0; nt < 24; nt++) {
    const int o = nt * 16 + m16;
    const int h = o / 48;
    const float sc = (slot < 8) ? INV_S384 : (2.f * softplusf(daa[h]) * (1.f / 48.f));
    const float bias = (slot == 0) ? bq[o] : 0.f;
#pragma unroll
    for (int rr = 0; rr < 4; rr++)
      es[(w * 16 + quad * 4 + rr) * QSTR + o] = f2bf((acc[nt][rr] + bias) * sc);
  }
  __syncthreads();
  for (int ch = t; ch < 512; ch += 256) {
    int r = ch >> 3, h = ch & 7;
    const uint4* sr = (const uint4*)&es[r * QSTR + h * 48];
    u16* dst = qsel + ((size_t)(b * 8 + h) * NQ + n0 + r) * KD + slot * 48;
#pragma unroll
    for (int j = 0; j < 6; j++) ((uint4*)dst)[j] = sr[j];
    if (slot == 10) {
      uint4 z = {0u, 0u, 0u, 0u};
      ((uint4*)dst)[6] = z;  // [528,536)
      ((uint4*)dst)[7] = z;  // [536,544)
    }
  }
}

// ---------------------------------------------------------------------------
// kv_mfma: grid (32 keyblks of 64, 27 tasks).  task<11: k-slot -> ksel (same
// structure as q_mfma, no scale).  task>=11: v component c=task-11 -> vT via
// [o][key] LDS staging (stride 72) and 8B key-contiguous stores.
// ---------------------------------------------------------------------------
#define VSTR 72
__global__ __launch_bounds__(256) void kv_mfma(
    const u16* __restrict__ xv, const u16* __restrict__ WkvB,
    const float* __restrict__ bkv, u16* __restrict__ ksel,
    u16* __restrict__ vT) {
  __shared__ __align__(16) u16 es[384 * VSTR];  // 55.3 KB (covers both uses)
  const int t = threadIdx.x;
  const int w = t >> 6, lane = t & 63, m16 = lane & 15, quad = lane >> 4;
  const int task = blockIdx.y;
  const int row0 = blockIdx.x * 64;
  const int b = row0 >> 8, n0 = row0 & 255;

  if (task < 11) {
    const int c = act_of(task), g = grade_of(c);
    f32x4 acc[24];
#pragma unroll
    for (int nt = 0; nt < 24; nt++) acc[nt] = (f32x4)0.f;
    const u16* ap = xv + ((size_t)c * 2048 + row0 + w * 16 + m16) * 64 + quad * 8;
    const u16* wb = WkvB + (size_t)g * 768 * 64 + (size_t)m16 * 64 + quad * 8;
#pragma unroll
    for (int ks = 0; ks < 2; ks++) {
      bf16x8 af = *(const bf16x8*)(ap + ks * 32);
#pragma unroll
      for (int nt = 0; nt < 24; nt++) {
        bf16x8 bf = *(const bf16x8*)(wb + (size_t)nt * 16 * 64 + ks * 32);
        acc[nt] = __builtin_amdgcn_mfma_f32_16x16x32_bf16(af, bf, acc[nt], 0, 0, 0);
      }
    }
#pragma unroll
    for (int nt = 0; nt < 24; nt++) {
      const int o = nt * 16 + m16;
      const float bias = (task == 0) ? bkv[o] : 0.f;
#pragma unroll
      for (int rr = 0; rr < 4; rr++)
        es[(w * 16 + quad * 4 + rr) * QSTR + o] = f2bf(acc[nt][rr] + bias);
    }
    __syncthreads();
    for (int ch = t; ch < 512; ch += 256) {
      int r = ch >> 3, h = ch & 7;
      const uint4* sr = (const uint4*)&es[r * QSTR + h * 48];
      u16* dst = ksel + ((size_t)(b * 8 + h) * NK + n0 + r) * KD + task * 48;
#pragma unroll
      for (int j = 0; j < 6; j++) ((uint4*)dst)[j] = sr[j];
      if (task == 10) {
        uint4 z = {0u, 0u, 0u, 0u};
        ((uint4*)dst)[6] = z;
        ((uint4*)dst)[7] = z;
      }
    }
  } else {
    const int c = task - 11, g = grade_of(c);
    f32x4 acc[24];
#pragma unroll
    for (int nt = 0; nt < 24; nt++) acc[nt] = (f32x4)0.f;
    const u16* ap = xv + ((size_t)c * 2048 + row0 + w * 16 + m16) * 64 + quad * 8;
    const u16* wb = WkvB + (size_t)g * 768 * 64 + (size_t)(384 + m16) * 64 + quad * 8;
#pragma unroll
    for (int ks = 0; ks < 2; ks++) {
      bf16x8 af = *(const bf16x8*)(ap + ks * 32);
#pragma unroll
      for (int nt = 0; nt < 24; nt++) {
        bf16x8 bf = *(const bf16x8*)(wb + (size_t)nt * 16 * 64 + ks * 32);
        acc[nt] = __builtin_amdgcn_mfma_f32_16x16x32_bf16(af, bf, acc[nt], 0, 0, 0);
      }
    }
#pragma unroll
    for (int nt = 0; nt < 24; nt++) {
      const int o = nt * 16 + m16;
      const float bias = (c == 0) ? bkv[384 + o] : 0.f;
#pragma unroll
      for (int rr = 0; rr < 4; rr++)
        es[o * VSTR + w * 16 + quad * 4 + rr] = f2bf(acc[nt][rr] + bias);
    }
    __syncthreads();
    for (int id = t; id < 6144; id += 256) {
      int o = id >> 4, part = id & 15;
      uint2 v = *(const uint2*)&es[o * VSTR + part * 4];
      int h = o / 48, oc = o - h * 48;
      *(uint2*)(vT + ((size_t)(b * 8 + h) * 768 + oc * 16 + c) * 256 + n0 + part * 4) = v;
    }
  }
}

// ---------------------------------------------------------------------------
// k2_kernel: kbias[bh*256+key] = -softplus(daa[h])/48 * sum(point k^2).
// Point slice is contiguous in ksel at [384,528).
// ---------------------------------------------------------------------------
__global__ __launch_bounds__(256) void k2_kernel(const u16* __restrict__ ksel,
                                                 const float* __restrict__ daa,
                                                 float* __restrict__ kbias) {
  int id = blockIdx.x * 256 + threadIdx.x;  // bh*256+key, < 16384
  const uint4* p = (const uint4*)(ksel + (size_t)id * KD + 384);
  float s = 0.f;
#pragma unroll
  for (int j = 0; j < 18; j++) {
    uint4 v = p[j];
    u32 a[4] = {v.x, v.y, v.z, v.w};
#pragma unroll
    for (int q = 0; q < 4; q++) {
      float lo = bf2f((u16)(a[q] & 0xFFFFu));
      float hi = bf2f((u16)(a[q] >> 16));
      s += lo * lo + hi * hi;
    }
  }
  int h = (id >> 8) & 7;
  kbias[id] = -(softplusf(daa[h]) * (1.f / 48.f)) * s;
}

// ---------------------------------------------------------------------------
// MFMA attention v10 (UNCHANGED from the 446us run; structural limit at
// 2 blocks/CU established by v7/v9/v10 A/Bs):
//  * QBLK=64, 2 blocks/CU (L2-thrash cliff at 3+), 2-deep QK^T pipeline,
//    1-deep V prefetch, in-register softmax, 96B-burst epilogue.
// ---------------------------------------------------------------------------
#define SPBW 268
#define STGW 26

#define QK_MFMA_BLOCK(AQ0, AQ1, AQ2, AQ3, AK0, AK1, AK2, AK3)                 \
  sacc[0][0] = __builtin_amdgcn_mfma_f32_16x16x32_bf16(AQ0, AK0, sacc[0][0], 0, 0, 0); \
  sacc[1][0] = __builtin_amdgcn_mfma_f32_16x16x32_bf16(AQ1, AK0, sacc[1][0], 0, 0, 0); \
  sacc[2][0] = __builtin_amdgcn_mfma_f32_16x16x32_bf16(AQ2, AK0, sacc[2][0], 0, 0, 0); \
  sacc[3][0] = __builtin_amdgcn_mfma_f32_16x16x32_bf16(AQ3, AK0, sacc[3][0], 0, 0, 0); \
  sacc[0][1] = __builtin_amdgcn_mfma_f32_16x16x32_bf16(AQ0, AK1, sacc[0][1], 0, 0, 0); \
  sacc[1][1] = __builtin_amdgcn_mfma_f32_16x16x32_bf16(AQ1, AK1, sacc[1][1], 0, 0, 0); \
  sacc[2][1] = __builtin_amdgcn_mfma_f32_16x16x32_bf16(AQ2, AK1, sacc[2][1], 0, 0, 0); \
  sacc[3][1] = __builtin_amdgcn_mfma_f32_16x16x32_bf16(AQ3, AK1, sacc[3][1], 0, 0, 0); \
  sacc[0][2] = __builtin_amdgcn_mfma_f32_16x16x32_bf16(AQ0, AK2, sacc[0][2], 0, 0, 0); \
  sacc[1][2] = __builtin_amdgcn_mfma_f32_16x16x32_bf16(AQ1, AK2, sacc[1][2], 0, 0, 0); \
  sacc[2][2] = __builtin_amdgcn_mfma_f32_16x16x32_bf16(AQ2, AK2, sacc[2][2], 0, 0, 0); \
  sacc[3][2] = __builtin_amdgcn_mfma_f32_16x16x32_bf16(AQ3, AK2, sacc[3][2], 0, 0, 0); \
  sacc[0][3] = __builtin_amdgcn_mfma_f32_16x16x32_bf16(AQ0, AK3, sacc[0][3], 0, 0, 0); \
  sacc[1][3] = __builtin_amdgcn_mfma_f32_16x16x32_bf16(AQ1, AK3, sacc[1][3], 0, 0, 0); \
  sacc[2][3] = __builtin_amdgcn_mfma_f32_16x16x32_bf16(AQ2, AK3, sacc[2][3], 0, 0, 0); \
  sacc[3][3] = __builtin_amdgcn_mfma_f32_16x16x32_bf16(AQ3, AK3, sacc[3][3], 0, 0, 0);

__global__ __launch_bounds__(256, 2) void attn_kernel(
    const u16* __restrict__ qsel, const u16* __restrict__ ksel,
    const float* __restrict__ kbias, const u16* __restrict__ vT,
    u16* __restrict__ ctxJ) {
  const int qt = blockIdx.x, h = blockIdx.y, b = blockIdx.z;
  const int g = b * 8 + h;

  const int t = threadIdx.x;
  const int w = t >> 6;
  const int lane = t & 63;
  const int m16 = lane & 15;
  const int quad = lane >> 4;

  // union: P (bf16, 64x268 = 34.3KB) then output staging (53.2KB)
  __shared__ __align__(16) u32 uni_s[13312];
  u16* spb = (u16*)uni_s;
  u32* stg = uni_s;
  __shared__ float kb[256];
  __shared__ __align__(16) float wred[64][4];
  __shared__ __align__(16) float wsum[64][4];

  const size_t bh = (size_t)g;
  const int n0 = qt * 64;
  const u16* qg = qsel + (bh * NQ + n0) * KD;
  const u16* kg = ksel + bh * NK * KD;
  const u16* vg = vT + bh * 768 * 256;

  kb[t] = kbias[bh * NK + t];
  __syncthreads();
  float kbr[4];
#pragma unroll
  for (int nt = 0; nt < 4; nt++) kbr[nt] = kb[w * 64 + nt * 16 + m16];

  f32x4 sacc[4][4];
#pragma unroll
  for (int mt = 0; mt < 4; mt++)
#pragma unroll
    for (int nt = 0; nt < 4; nt++) sacc[mt][nt] = (f32x4)0.f;

  // ---- QK^T: 17 K-steps, 2-deep software pipeline ----
  const u16* qp0 = qg + (size_t)m16 * KD + quad * 8;
  const u16* qp1 = qg + (size_t)(16 + m16) * KD + quad * 8;
  const u16* qp2 = qg + (size_t)(32 + m16) * KD + quad * 8;
  const u16* qp3 = qg + (size_t)(48 + m16) * KD + quad * 8;
  const u16* kp = kg + (size_t)(w * 64 + m16) * KD + quad * 8;
  bf16x8 cq0 = *(const bf16x8*)qp0;
  bf16x8 cq1 = *(const bf16x8*)qp1;
  bf16x8 cq2 = *(const bf16x8*)qp2;
  bf16x8 cq3 = *(const bf16x8*)qp3;
  bf16x8 ck0 = *(const bf16x8*)(kp);
  bf16x8 ck1 = *(const bf16x8*)(kp + 16 * KD);
  bf16x8 ck2 = *(const bf16x8*)(kp + 32 * KD);
  bf16x8 ck3 = *(const bf16x8*)(kp + 48 * KD);
  bf16x8 dq0 = *(const bf16x8*)(qp0 + 32);
  bf16x8 dq1 = *(const bf16x8*)(qp1 + 32);
  bf16x8 dq2 = *(const bf16x8*)(qp2 + 32);
  bf16x8 dq3 = *(const bf16x8*)(qp3 + 32);
  bf16x8 dk0 = *(const bf16x8*)(kp + 32);
  bf16x8 dk1 = *(const bf16x8*)(kp + 16 * KD + 32);
  bf16x8 dk2 = *(const bf16x8*)(kp + 32 * KD + 32);
  bf16x8 dk3 = *(const bf16x8*)(kp + 48 * KD + 32);
  for (int i = 0; i < 7; i++) {
    const int oA = (2 * i + 2) * 32;
    bf16x8 nq0 = *(const bf16x8*)(qp0 + oA);
    bf16x8 nq1 = *(const bf16x8*)(qp1 + oA);
    bf16x8 nq2 = *(const bf16x8*)(qp2 + oA);
    bf16x8 nq3 = *(const bf16x8*)(qp3 + oA);
    bf16x8 nk0 = *(const bf16x8*)(kp + oA);
    bf16x8 nk1 = *(const bf16x8*)(kp + 16 * KD + oA);
    bf16x8 nk2 = *(const bf16x8*)(kp + 32 * KD + oA);
    bf16x8 nk3 = *(const bf16x8*)(kp + 48 * KD + oA);
    const int oB = (2 * i + 3) * 32;
    bf16x8 mq0 = *(const bf16x8*)(qp0 + oB);
    bf16x8 mq1 = *(const bf16x8*)(qp1 + oB);
    bf16x8 mq2 = *(const bf16x8*)(qp2 + oB);
    bf16x8 mq3 = *(const bf16x8*)(qp3 + oB);
    bf16x8 mk0 = *(const bf16x8*)(kp + oB);
    bf16x8 mk1 = *(const bf16x8*)(kp + 16 * KD + oB);
    bf16x8 mk2 = *(const bf16x8*)(kp + 32 * KD + oB);
    bf16x8 mk3 = *(const bf16x8*)(kp + 48 * KD + oB);
    QK_MFMA_BLOCK(cq0, cq1, cq2, cq3, ck0, ck1, ck2, ck3)
    QK_MFMA_BLOCK(dq0, dq1, dq2, dq3, dk0, dk1, dk2, dk3)
    cq0 = nq0; cq1 = nq1; cq2 = nq2; cq3 = nq3;
    ck0 = nk0; ck1 = nk1; ck2 = nk2; ck3 = nk3;
    dq0 = mq0; dq1 = mq1; dq2 = mq2; dq3 = mq3;
    dk0 = mk0; dk1 = mk1; dk2 = mk2; dk3 = mk3;
  }
  {
    const int oT = 16 * 32;
    bf16x8 nq0 = *(const bf16x8*)(qp0 + oT);
    bf16x8 nq1 = *(const bf16x8*)(qp1 + oT);
    bf16x8 nq2 = *(const bf16x8*)(qp2 + oT);
    bf16x8 nq3 = *(const bf16x8*)(qp3 + oT);
    bf16x8 nk0 = *(const bf16x8*)(kp + oT);
    bf16x8 nk1 = *(const bf16x8*)(kp + 16 * KD + oT);
    bf16x8 nk2 = *(const bf16x8*)(kp + 32 * KD + oT);
    bf16x8 nk3 = *(const bf16x8*)(kp + 48 * KD + oT);
    QK_MFMA_BLOCK(cq0, cq1, cq2, cq3, ck0, ck1, ck2, ck3)
    QK_MFMA_BLOCK(dq0, dq1, dq2, dq3, dk0, dk1, dk2, dk3)
    QK_MFMA_BLOCK(nq0, nq1, nq2, nq3, nk0, nk1, nk2, nk3)
  }

  // ---- softmax, in-register ----
#pragma unroll
  for (int mt = 0; mt < 4; mt++)
#pragma unroll
    for (int rr = 0; rr < 4; rr++) {
      float a0 = sacc[mt][0][rr] + kbr[0];
      float a1 = sacc[mt][1][rr] + kbr[1];
      float a2 = sacc[mt][2][rr] + kbr[2];
      float a3 = sacc[mt][3][rr] + kbr[3];
      sacc[mt][0][rr] = a0; sacc[mt][1][rr] = a1;
      sacc[mt][2][rr] = a2; sacc[mt][3][rr] = a3;
      float m = fmaxf(fmaxf(a0, a1), fmaxf(a2, a3));
#pragma unroll
      for (int off = 1; off < 16; off <<= 1)
        m = fmaxf(m, __shfl_xor(m, off));
      if (m16 == mt * 4 + rr) wred[mt * 16 + quad * 4 + rr][w] = m;
    }
  __syncthreads();
#pragma unroll
  for (int mt = 0; mt < 4; mt++)
#pragma unroll
    for (int rr = 0; rr < 4; rr++) {
      const int row = mt * 16 + quad * 4 + rr;
      float4 m4 = *(const float4*)wred[row];
      const float gm = fmaxf(fmaxf(m4.x, m4.y), fmaxf(m4.z, m4.w));
      float s = 0.f;
#pragma unroll
      for (int nt = 0; nt < 4; nt++) {
        float e = __expf(sacc[mt][nt][rr] - gm);
        s += e;
        spb[row * SPBW + w * 64 + nt * 16 + m16] = f2bf(e);
      }
#pragma unroll
      for (int off = 1; off < 16; off <<= 1)
        s += __shfl_xor(s, off);
      if (m16 == mt * 4 + rr) wsum[row][w] = s;
    }
  __syncthreads();

  // ---- PV: D[m=q-row][n=d]; 1-deep V prefetch ----
  f32x4 oacc[4][12];
#pragma unroll
  for (int mt = 0; mt < 4; mt++)
#pragma unroll
    for (int nt = 0; nt < 12; nt++) oacc[mt][nt] = (f32x4)0.f;

  const u16* vp = vg + (size_t)(w * 192 + m16) * 256 + quad * 8;
  bf16x8 vc[12];
#pragma unroll
  for (int nt = 0; nt < 12; nt++)
    vc[nt] = *(const bf16x8*)(vp + (size_t)nt * 16 * 256);
#pragma unroll
  for (int ks = 0; ks < 8; ks++) {
    bf16x8 vn[12];
    if (ks < 7) {
#pragma unroll
      for (int nt = 0; nt < 12; nt++)
        vn[nt] = *(const bf16x8*)(vp + (size_t)nt * 16 * 256 + (ks + 1) * 32);
    }
    bf16x8 pa0 = *(const bf16x8*)(&spb[(size_t)m16 * SPBW + ks * 32 + quad * 8]);
    bf16x8 pa1 = *(const bf16x8*)(&spb[(size_t)(16 + m16) * SPBW + ks * 32 + quad * 8]);
    bf16x8 pa2 = *(const bf16x8*)(&spb[(size_t)(32 + m16) * SPBW + ks * 32 + quad * 8]);
    bf16x8 pa3 = *(const bf16x8*)(&spb[(size_t)(48 + m16) * SPBW + ks * 32 + quad * 8]);
#pragma unroll
    for (int nt = 0; nt < 12; nt++) {
      oacc[0][nt] = __builtin_amdgcn_mfma_f32_16x16x32_bf16(pa0, vc[nt], oacc[0][nt], 0, 0, 0);
      oacc[1][nt] = __builtin_amdgcn_mfma_f32_16x16x32_bf16(pa1, vc[nt], oacc[1][nt], 0, 0, 0);
      oacc[2][nt] = __builtin_amdgcn_mfma_f32_16x16x32_bf16(pa2, vc[nt], oacc[2][nt], 0, 0, 0);
      oacc[3][nt] = __builtin_amdgcn_mfma_f32_16x16x32_bf16(pa3, vc[nt], oacc[3][nt], 0, 0, 0);
    }
    if (ks < 7) {
#pragma unroll
      for (int nt = 0; nt < 12; nt++) vc[nt] = vn[nt];
    }
  }

  // ---- staged epilogue: 2 chunks of 8 c; full 96B runs per thread ----
  const size_t rowbase = (size_t)b * NQ + n0;
#pragma unroll
  for (int ch2 = 0; ch2 < 2; ch2++) {
    __syncthreads();
    if ((m16 >> 3) == ch2) {
      const int c8 = m16 & 7;
#pragma unroll
      for (int mt = 0; mt < 4; mt++)
#pragma unroll
        for (int rr = 0; rr < 4; rr++) {
          const int row = mt * 16 + quad * 4 + rr;
          float4 s4 = *(const float4*)wsum[row];
          const float iv = 1.f / (s4.x + s4.y + s4.z + s4.w);
          u32* dp = stg + (row * 8 + c8) * STGW + w * 6;
#pragma unroll
          for (int j = 0; j < 6; j++) {
            u32 lo = f2bf(oacc[mt][2 * j][rr] * iv);
            u32 hi = f2bf(oacc[mt][2 * j + 1][rr] * iv);
            dp[j] = lo | (hi << 16);
          }
        }
    }
    __syncthreads();
    for (int ch = t; ch < 512; ch += 256) {
      const int prow = ch >> 3, pc8 = ch & 7;
      const u32* sp2 = stg + (prow * 8 + pc8) * STGW;
      u16* dst = ctxJ + ((size_t)(ch2 * 8 + pc8) * 8192 + rowbase + prow) * 384 + h * 48;
#pragma unroll
      for (int j6 = 0; j6 < 6; j6++) {
        uint2 a = *(const uint2*)(sp2 + j6 * 4);
        uint2 bb2 = *(const uint2*)(sp2 + j6 * 4 + 2);
        uint4 v4v = {a.x, a.y, bb2.x, bb2.y};
        *(uint4*)(dst + j6 * 8) = v4v;
      }
    }
  }
}

// ---------------------------------------------------------------------------
// out_kernel v5: 16 rows/block, grid 512 -> 2 blocks/CU (was 256 blocks =
// exactly 1/CU with no inter-block latency hiding).  Same wave=component
// structure, single pass (ch loop removed).
// ---------------------------------------------------------------------------
#define ESTR2 785
__global__ __launch_bounds__(1024) void out_kernel(
    const u16* __restrict__ ctxJ, const u16* __restrict__ WoB,
    const float* __restrict__ bo, const float* __restrict__ hidden,
    float* __restrict__ out) {
  __shared__ __align__(16) float es[16 * ESTR2];  // 50.2 KB
  const int t = threadIdx.x;
  const int c = __builtin_amdgcn_readfirstlane(t >> 6);
  const int lane = t & 63;
  const int m16 = lane & 15, quad = lane >> 4;
  const int r0 = blockIdx.x * 16;
  const int g = grade_of(c);
  const u16* wb = WoB + (size_t)g * 48 * 384;

  f32x4 acc[3];
#pragma unroll
  for (int nt = 0; nt < 3; nt++) acc[nt] = (f32x4)0.f;
  const u16* ap = ctxJ + ((size_t)c * 8192 + r0 + m16) * 384 + quad * 8;
#pragma unroll 4
  for (int ks = 0; ks < 12; ks++) {
    bf16x8 af = *(const bf16x8*)(ap + ks * 32);
#pragma unroll
    for (int nt = 0; nt < 3; nt++) {
      bf16x8 bf = *(const bf16x8*)(wb + (size_t)(nt * 16 + m16) * 384 + ks * 32 + quad * 8);
      acc[nt] = __builtin_amdgcn_mfma_f32_16x16x32_bf16(af, bf, acc[nt], 0, 0, 0);
    }
  }
  __syncthreads();
#pragma unroll
  for (int nt = 0; nt < 3; nt++)
#pragma unroll
    for (int rr = 0; rr < 4; rr++)
      es[(quad * 4 + rr) * ESTR2 + c * 49 + nt * 16 + m16] = acc[nt][rr];
  __syncthreads();
#pragma unroll
  for (int k = 0; k < 3; k++) {
    int m4 = t + 1024 * k;
    int r = m4 / 192;
    int col0 = (m4 - r * 192) * 4;
    int o = col0 >> 4, cb = col0 & 15;
    const float* er = &es[r * ESTR2 + o];
    float4 v;
    v.x = er[(cb + 0) * 49];
    v.y = er[(cb + 1) * 49];
    v.z = er[(cb + 2) * 49];
    v.w = er[(cb + 3) * 49];
    if (cb == 0) v.x += bo[o];
    size_t gidx = (size_t)(r0 + r) * 768 + col0;
    const float4 hv = *(const float4*)&hidden[gidx];
    v.x += hv.x; v.y += hv.y; v.z += hv.z; v.w += hv.w;
    *(float4*)&out[gidx] = v;
  }
}

// ---------------------------------------------------------------------------
extern "C" void kernel_launch(void* const* d_in, const int* in_sizes, int n_in,
                              void* d_out, int out_size, void* d_ws, size_t ws_size,
                              hipStream_t stream) {
  const float* hidden = (const float*)d_in[0];
  const float* vis = (const float*)d_in[1];
  const float* lnw = (const float*)d_in[2];
  const float* Wq = (const float*)d_in[3];
  const float* bq = (const float*)d_in[4];
  const float* Wkv = (const float*)d_in[5];
  const float* bkv = (const float*)d_in[6];
  const float* Wo = (const float*)d_in[7];
  const float* bo = (const float*)d_in[8];
  const float* daa = (const float*)d_in[9];
  float* out = (float*)d_out;

  char* ws = (char*)d_ws;
  size_t off = 0;
  auto carve = [&](size_t bytes) -> void* {
    void* p = ws + off;
    off += (bytes + 255) & ~(size_t)255;
    return p;
  };
  u16* WqB = (u16*)carve((size_t)5 * 384 * 64 * 2);
  u16* WkvB = (u16*)carve((size_t)5 * 768 * 64 * 2);
  u16* WoB = (u16*)carve((size_t)5 * 48 * 384 * 2);
  u16* qsel = (u16*)carve((size_t)BB * HH * NQ * KD * 2);
  u16* ksel = (u16*)carve((size_t)BB * HH * NK * KD * 2);
  u16* vT = (u16*)carve((size_t)BB * HH * 768 * 256 * 2);
  float* kbias = (float*)carve((size_t)BB * HH * NK * 4);
  // union: [xq | xv] consumed by q/kv, then ctxJ ([c][row][384]) overwrites
  char* uni = (char*)carve((size_t)16 * 384 * 8192 * 2);
  u16* ctxJ = (u16*)uni;
  u16* xq = (u16*)uni;                                      // 16 MB
  u16* xv = (u16*)(uni + (size_t)16 * 8192 * 64 * 2);       // 4 MB

  wB_kernel<<<1800, 256, 0, stream>>>(Wq, Wkv, Wo, WqB, WkvB, WoB);
  xJ_kernel<<<BB * NQ / 64, 256, 0, stream>>>(hidden, xq, lnw, BB * NQ, 1);
  xJ_kernel<<<BB * NK / 64, 256, 0, stream>>>(vis, xv, nullptr, BB * NK, 0);
  kv_mfma<<<dim3(BB * NK / 64, 27), 256, 0, stream>>>(xv, WkvB, bkv, ksel, vT);
  k2_kernel<<<64, 256, 0, stream>>>(ksel, daa, kbias);
  q_mfma<<<dim3(BB * NQ / 64, 11), 256, 0, stream>>>(xq, WqB, bq, daa, qsel);
  attn_kernel<<<dim3(NQ / 64, HH, BB), 256, 0, stream>>>(qsel, ksel, kbias, vT, ctxJ);
  out_kernel<<<512, 1024, 0, stream>>>(ctxJ, WoB, bo, hidden, out);
}